// Round 5
// baseline (299.278 us; speedup 1.0000x reference)
//
#include <hip/hip_runtime.h>
#include <math.h>

#define FINF 3.0e38f

// ---------------- init small scratch ----------------
__global__ void k_init(unsigned* __restrict__ hist, int* __restrict__ cnt) {
  int i = blockIdx.x * 256 + threadIdx.x;
  if (i < 16 * 4096) hist[i] = 0u;
  if (i < 16) cnt[i] = 0;
}

// ---------------- transpose W1 (128,256,3,3) -> wt[ic][tap][oc] ----------------
__global__ void k_wt(const float* __restrict__ w1, float* __restrict__ wt) {
  const int idx = blockIdx.x * 256 + threadIdx.x;  // 294912 = 256*9*128
  if (idx >= 294912) return;
  const int oc = idx & 127;
  const int r = idx >> 7;
  const int tap = r % 9;
  const int ic = r / 9;
  wt[idx] = w1[((size_t)oc * 256 + ic) * 9 + tap];
}

// ---------------- conv1: latent(16,256,32,32) * W1 s2 p1 -> 8 ksplit partials ----------------
// grid (16 b, 16 ocg, 8 ks), block 256 (one output pixel each), 8 oc per thread, 32 ic per block.
// Double-buffered LDS pipeline: global loads for chunk cc+1 issue before computing chunk cc,
// so HBM/L2 latency hides under ~600 cycles of FMA issue. Weights are uniform-address ->
// scalar (SGPR) loads. Stencil reads are branchless (clamped addr + select).
__global__ __launch_bounds__(256) void k_conv1(const float* __restrict__ lat,
                                               const float* __restrict__ wt,
                                               float* __restrict__ h1part) {
  const int b = blockIdx.x, ocg = blockIdx.y, ks = blockIdx.z;
  const int t = threadIdx.x;
  const int oy = t >> 4, ox = t & 15;
  __shared__ float sIn[2][4096];  // 2 x (4 channels x 32x32) = 32 KB
  float acc[8];
#pragma unroll
  for (int j = 0; j < 8; ++j) acc[j] = 0.f;
  const int ocb = ocg * 8;
  const int icb = ks * 32;

  // precompute stencil addresses (clamped) + validity masks
  int sad[9];
  bool sok[9];
#pragma unroll
  for (int ky = 0; ky < 3; ++ky)
#pragma unroll
    for (int kx = 0; kx < 3; ++kx) {
      const int iy = 2 * oy - 1 + ky, ix = 2 * ox - 1 + kx;
      sok[ky * 3 + kx] = (iy >= 0) && (ix >= 0);
      sad[ky * 3 + kx] = (iy >= 0 ? iy : 0) * 32 + (ix >= 0 ? ix : 0);
    }

  // prologue: stage chunk 0
  {
    const float4* src = (const float4*)lat + ((size_t)b * 256 + icb) * 256;
    float4 p0 = src[t], p1 = src[256 + t], p2 = src[512 + t], p3 = src[768 + t];
    ((float4*)sIn[0])[t] = p0;
    ((float4*)sIn[0])[256 + t] = p1;
    ((float4*)sIn[0])[512 + t] = p2;
    ((float4*)sIn[0])[768 + t] = p3;
  }
  __syncthreads();

  float4 r0, r1, r2, r3;
#pragma unroll 1
  for (int cc = 0; cc < 8; ++cc) {
    const int p = cc & 1;
    if (cc < 7) {  // issue next chunk's global loads early
      const float4* s2 = (const float4*)lat + ((size_t)b * 256 + icb + (cc + 1) * 4) * 256;
      r0 = s2[t]; r1 = s2[256 + t]; r2 = s2[512 + t]; r3 = s2[768 + t];
    }
    const float* buf = sIn[p];
#pragma unroll
    for (int ic = 0; ic < 4; ++ic) {
      const float* ib = buf + ic * 1024;
      const float* wp = wt + (size_t)(icb + cc * 4 + ic) * 1152 + ocb;
      float4 wv[18];  // uniform addresses -> SGPR burst
#pragma unroll
      for (int tap = 0; tap < 9; ++tap) {
        wv[2 * tap]     = *(const float4*)(wp + tap * 128);
        wv[2 * tap + 1] = *(const float4*)(wp + tap * 128 + 4);
      }
      float v[9];
#pragma unroll
      for (int tap = 0; tap < 9; ++tap) {
        const float lv = ib[sad[tap]];
        v[tap] = sok[tap] ? lv : 0.f;
      }
#pragma unroll
      for (int tap = 0; tap < 9; ++tap) {
        const float vv = v[tap];
        const float4 wa = wv[2 * tap];
        const float4 wb = wv[2 * tap + 1];
        acc[0] = fmaf(wa.x, vv, acc[0]);
        acc[1] = fmaf(wa.y, vv, acc[1]);
        acc[2] = fmaf(wa.z, vv, acc[2]);
        acc[3] = fmaf(wa.w, vv, acc[3]);
        acc[4] = fmaf(wb.x, vv, acc[4]);
        acc[5] = fmaf(wb.y, vv, acc[5]);
        acc[6] = fmaf(wb.z, vv, acc[6]);
        acc[7] = fmaf(wb.w, vv, acc[7]);
      }
    }
    if (cc < 7) {  // stage next chunk into the other buffer; one barrier per iter
      float* nb = sIn[p ^ 1];
      ((float4*)nb)[t] = r0;
      ((float4*)nb)[256 + t] = r1;
      ((float4*)nb)[512 + t] = r2;
      ((float4*)nb)[768 + t] = r3;
      __syncthreads();
    }
  }
  float* dst = h1part + (size_t)ks * 524288 + ((size_t)b * 128 + ocb) * 256 + t;
#pragma unroll
  for (int j = 0; j < 8; ++j) dst[j * 256] = acc[j];
}

// ---------------- combine 8 ksplit partials + bias + leaky ----------------
__global__ void k_combine(const float* __restrict__ h1p, float* __restrict__ h1,
                          const float* __restrict__ b1) {
  const int i = blockIdx.x * 256 + threadIdx.x;  // float4 index, 131072 total
  const float4* p = (const float4*)h1p;
  float4 a = p[i];
#pragma unroll
  for (int ks = 1; ks < 8; ++ks) {
    const float4 q = p[(size_t)ks * 131072 + i];
    a.x += q.x; a.y += q.y; a.z += q.z; a.w += q.w;
  }
  const int oc = (i >> 6) & 127;
  const float bias = b1[oc];
  float s;
  s = a.x + bias; a.x = s >= 0.f ? s : 0.02f * s;
  s = a.y + bias; a.y = s >= 0.f ? s : 0.02f * s;
  s = a.z + bias; a.z = s >= 0.f ? s : 0.02f * s;
  s = a.w + bias; a.w = s >= 0.f ? s : 0.02f * s;
  ((float4*)h1)[i] = a;
}

// ---------------- conv2 + mean + 1x1 conv + tanh -> params[b] ----------------
__global__ __launch_bounds__(256) void k_conv2(const float* __restrict__ h1,
                                               const float* __restrict__ w2,
                                               const float* __restrict__ b2,
                                               const float* __restrict__ w3,
                                               const float* __restrict__ b3,
                                               float* __restrict__ params) {
  const int b = blockIdx.x;
  const int t = threadIdx.x;
  __shared__ float sW[1152];
  __shared__ float red[256];
  for (int i = t; i < 1152; i += 256) sW[i] = w2[i];
  __syncthreads();
  const int pix = t >> 2, icq = t & 3;
  const int oy = pix >> 3, ox = pix & 7;
  const float* hb = h1 + (size_t)b * 128 * 256;
  float s = 0.f;
  for (int ic = icq * 32; ic < icq * 32 + 32; ++ic) {
    const float* hp = hb + ic * 256;
#pragma unroll
    for (int ky = 0; ky < 3; ++ky) {
      const int iy = 2 * oy - 1 + ky;
      if (iy < 0) continue;
#pragma unroll
      for (int kx = 0; kx < 3; ++kx) {
        const int ix = 2 * ox - 1 + kx;
        if (ix < 0) continue;
        s += sW[ic * 9 + ky * 3 + kx] * hp[iy * 16 + ix];
      }
    }
  }
  red[t] = s;
  __syncthreads();
  for (int off = 128; off > 0; off >>= 1) {
    if (t < off) red[t] += red[t + off];
    __syncthreads();
  }
  if (t == 0) {
    const float mean = red[0] / 64.f + b2[0];
    const float h = w3[0] * mean + b3[0];
    params[b] = tanhf(h) * 0.5f + 0.5f;
  }
}

// ---------------- histogram of dark channel (also writes dc) ----------------
__global__ __launch_bounds__(256) void k_hist(const float* __restrict__ x,
                                              unsigned* __restrict__ ghist,
                                              float* __restrict__ dc) {
  const int b = blockIdx.y, blk = blockIdx.x, t = threadIdx.x;
  __shared__ unsigned lh[4096];
  for (int i = t; i < 4096; i += 256) lh[i] = 0u;
  __syncthreads();
  const float* xr = x + (size_t)b * 3 * 262144;
  const float* xg = xr + 262144;
  const float* xb = xg + 262144;
  float4* dcb = (float4*)(dc + (size_t)b * 262144);
  const int f0 = blk * 2048;
#pragma unroll
  for (int i = 0; i < 8; ++i) {
    const int f4 = f0 + t + i * 256;
    const float4 r = ((const float4*)xr)[f4];
    const float4 g = ((const float4*)xg)[f4];
    const float4 bl = ((const float4*)xb)[f4];
    float4 d4;
    d4.x = fminf(fminf(r.x, g.x), bl.x); atomicAdd(&lh[min(4095, (int)(d4.x * 4096.f))], 1u);
    d4.y = fminf(fminf(r.y, g.y), bl.y); atomicAdd(&lh[min(4095, (int)(d4.y * 4096.f))], 1u);
    d4.z = fminf(fminf(r.z, g.z), bl.z); atomicAdd(&lh[min(4095, (int)(d4.z * 4096.f))], 1u);
    d4.w = fminf(fminf(r.w, g.w), bl.w); atomicAdd(&lh[min(4095, (int)(d4.w * 4096.f))], 1u);
    dcb[f4] = d4;
  }
  __syncthreads();
  for (int i = t; i < 4096; i += 256)
    if (lh[i]) atomicAdd(&ghist[b * 4096 + i], lh[i]);
}

// ---------------- suffix scan from top to find threshold bin ----------------
__global__ __launch_bounds__(256) void k_scan(const unsigned* __restrict__ ghist,
                                              int* __restrict__ Bbin, int* __restrict__ rneed) {
  const int b = blockIdx.x, t = threadIdx.x;
  __shared__ unsigned h[4096];
  __shared__ unsigned csum[256];
  for (int i = t; i < 4096; i += 256) h[i] = ghist[b * 4096 + i];
  __syncthreads();
  const int top = 4095 - 16 * t;
  unsigned s = 0;
#pragma unroll
  for (int k = 0; k < 16; ++k) s += h[top - k];
  csum[t] = s;
  __syncthreads();
  for (int off = 1; off < 256; off <<= 1) {
    const unsigned add = (t >= off) ? csum[t - off] : 0u;
    __syncthreads();
    csum[t] += add;
    __syncthreads();
  }
  const unsigned incl = csum[t];
  const unsigned before = incl - s;
  if (before < 262u && incl >= 262u) {
    unsigned cum = before;
    for (int k = 0; k < 16; ++k) {
      const unsigned c = h[top - k];
      if (cum + c >= 262u) { Bbin[b] = top - k; rneed[b] = (int)(262u - cum); break; }
      cum += c;
    }
  }
}

// ---------------- collect: reads dc; sparse RGB fetches for selected pixels ----------------
__global__ __launch_bounds__(256) void k_collect(const float* __restrict__ x,
                                                 const float* __restrict__ dc,
                                                 const int* __restrict__ Bbin,
                                                 int* __restrict__ cnt,
                                                 float* __restrict__ candv,
                                                 int* __restrict__ candi,
                                                 float* __restrict__ bsums) {
  const int b = blockIdx.y, blk = blockIdx.x, t = threadIdx.x;
  const int B = Bbin[b];
  const float* xr = x + (size_t)b * 3 * 262144;
  const float* xg = xr + 262144;
  const float* xb = xg + 262144;
  const float4* dcb = (const float4*)(dc + (size_t)b * 262144);
  const int f0 = blk * 2048;
  float s0 = 0.f, s1 = 0.f, s2 = 0.f;
#pragma unroll
  for (int i = 0; i < 8; ++i) {
    const int f4 = f0 + t + i * 256;
    const float4 d4 = dcb[f4];
    const float dv[4] = {d4.x, d4.y, d4.z, d4.w};
#pragma unroll
    for (int j = 0; j < 4; ++j) {
      const int bin = min(4095, (int)(dv[j] * 4096.f));
      if (bin >= B) {
        const int idx = f4 * 4 + j;
        if (bin > B) {
          s0 += xr[idx]; s1 += xg[idx]; s2 += xb[idx];
        } else {
          const int k = atomicAdd(&cnt[b], 1);
          if (k < 4096) { candv[b * 4096 + k] = dv[j]; candi[b * 4096 + k] = idx; }
        }
      }
    }
  }
  __shared__ float red[256];
  red[t] = s0; __syncthreads();
  for (int off = 128; off > 0; off >>= 1) { if (t < off) red[t] += red[t + off]; __syncthreads(); }
  if (t == 0) bsums[((size_t)b * 32 + blk) * 3 + 0] = red[0];
  __syncthreads();
  red[t] = s1; __syncthreads();
  for (int off = 128; off > 0; off >>= 1) { if (t < off) red[t] += red[t + off]; __syncthreads(); }
  if (t == 0) bsums[((size_t)b * 32 + blk) * 3 + 1] = red[0];
  __syncthreads();
  red[t] = s2; __syncthreads();
  for (int off = 128; off > 0; off >>= 1) { if (t < off) red[t] += red[t + off]; __syncthreads(); }
  if (t == 0) bsums[((size_t)b * 32 + blk) * 3 + 2] = red[0];
}

// ---------------- finalize A (deterministic; tie-break value desc, index asc) ----------------
__global__ void k_finalA(const float* __restrict__ x, const float* __restrict__ bsums,
                         const int* __restrict__ cnt, const int* __restrict__ rneed,
                         float* __restrict__ candv, const int* __restrict__ candi,
                         float* __restrict__ Av) {
  const int b = blockIdx.x;
  if (threadIdx.x != 0) return;
  float S0 = 0.f, S1 = 0.f, S2 = 0.f;
  for (int k = 0; k < 32; ++k) {
    S0 += bsums[((size_t)b * 32 + k) * 3 + 0];
    S1 += bsums[((size_t)b * 32 + k) * 3 + 1];
    S2 += bsums[((size_t)b * 32 + k) * 3 + 2];
  }
  const int n = min(cnt[b], 4096);
  const int r = rneed[b];
  const float* xr = x + (size_t)b * 3 * 262144;
  const float* xg = xr + 262144;
  const float* xb = xg + 262144;
  for (int sel = 0; sel < r; ++sel) {
    int best = -1; float bv = -1.f; int bi = 0x7FFFFFFF;
    for (int i = 0; i < n; ++i) {
      const float v = candv[b * 4096 + i];
      const int id = candi[b * 4096 + i];
      if (v > bv || (v == bv && id < bi)) { best = i; bv = v; bi = id; }
    }
    if (best < 0) break;
    candv[b * 4096 + best] = -1.f;
    S0 += xr[bi]; S1 += xg[bi]; S2 += xb[bi];
  }
  Av[b * 3 + 0] = S0 / 262.f;
  Av[b * 3 + 1] = S1 / 262.f;
  Av[b * 3 + 2] = S2 / 262.f;
}

// ---------------- dc2 + horizontal 7-min (XCD-swizzled) ----------------
__global__ __launch_bounds__(256) void k_dch(const float* __restrict__ x,
                                             const float* __restrict__ Av,
                                             float* __restrict__ dcH) {
  // 8192 blocks; chunked XCD swizzle: each XCD gets 2 whole images
  const int lid = blockIdx.y * gridDim.x + blockIdx.x;
  const int swz = (lid & 7) * 1024 + (lid >> 3);
  const int y = swz & 511, b = swz >> 9;
  const int t = threadIdx.x;
  __shared__ float srow[518];
  const float a0 = Av[b * 3 + 0], a1 = Av[b * 3 + 1], a2 = Av[b * 3 + 2];
  const size_t rowoff = (size_t)b * 3 * 262144 + (size_t)y * 512;
  const float* xr = x + rowoff;
  const float* xg = xr + 262144;
  const float* xb = xg + 262144;
  const float2 r = ((const float2*)xr)[t];
  const float2 g = ((const float2*)xg)[t];
  const float2 bl = ((const float2*)xb)[t];
  srow[3 + 2 * t + 0] = fminf(fminf(r.x / a0, g.x / a1), bl.x / a2);
  srow[3 + 2 * t + 1] = fminf(fminf(r.y / a0, g.y / a1), bl.y / a2);
  if (t < 3) { srow[t] = FINF; srow[515 + t] = FINF; }
  __syncthreads();
  float2 o;
  float m = srow[2 * t];
#pragma unroll
  for (int k = 1; k < 7; ++k) m = fminf(m, srow[2 * t + k]);
  o.x = m;
  m = srow[2 * t + 1];
#pragma unroll
  for (int k = 1; k < 7; ++k) m = fminf(m, srow[2 * t + 1 + k]);
  o.y = m;
  ((float2*)(dcH + ((size_t)b * 512 + y) * 512))[t] = o;
}

// ---------------- final: vertical 7-min + transmission + dehaze; per-block minmax partials ----------------
__global__ __launch_bounds__(256) void k_final(const float* __restrict__ x,
                                               const float* __restrict__ dcH,
                                               const float* __restrict__ params,
                                               const float* __restrict__ Av,
                                               float* __restrict__ out,
                                               float2* __restrict__ pmm) {
  const int lid = blockIdx.y * gridDim.x + blockIdx.x;
  const int swz = (lid & 7) * 1024 + (lid >> 3);  // same mapping as k_dch -> dcH is L2-local
  const int y = swz & 511, b = swz >> 9;
  const int t = threadIdx.x;
  const float pb = params[b];
  const float a0 = Av[b * 3 + 0], a1 = Av[b * 3 + 1], a2 = Av[b * 3 + 2];
  const float* dH = dcH + (size_t)b * 262144;
  float2 vm = make_float2(FINF, FINF);
#pragma unroll
  for (int dy = -3; dy <= 3; ++dy) {
    const int yy = y + dy;
    if (yy < 0 || yy > 511) continue;
    const float2 v = ((const float2*)(dH + (size_t)yy * 512))[t];
    vm.x = fminf(vm.x, v.x);
    vm.y = fminf(vm.y, v.y);
  }
  const float T0 = fmaxf(1.f - pb * vm.x, 0.01f);
  const float T1 = fmaxf(1.f - pb * vm.y, 0.01f);
  const float i0 = 1.f / T0;
  const float i1 = 1.f / T1;
  const size_t rowoff = (size_t)b * 3 * 262144 + (size_t)y * 512;
  float lmin = FINF, lmax = -FINF;
#pragma unroll
  for (int c = 0; c < 3; ++c) {
    const float a = (c == 0) ? a0 : ((c == 1) ? a1 : a2);
    const float2 xv = ((const float2*)(x + rowoff + (size_t)c * 262144))[t];
    const float o0 = fmaf(xv.x - a, i0, a);
    const float o1 = fmaf(xv.y - a, i1, a);
    lmin = fminf(lmin, fminf(o0, o1));
    lmax = fmaxf(lmax, fmaxf(o0, o1));
    ((float2*)(out + rowoff + (size_t)c * 262144))[t] = make_float2(o0, o1);
  }
  __shared__ float red[256];
  red[t] = lmin; __syncthreads();
  for (int off = 128; off > 0; off >>= 1) { if (t < off) red[t] = fminf(red[t], red[t + off]); __syncthreads(); }
  const float bmin = red[0];
  __syncthreads();
  red[t] = lmax; __syncthreads();
  for (int off = 128; off > 0; off >>= 1) { if (t < off) red[t] = fmaxf(red[t], red[t + off]); __syncthreads(); }
  if (t == 0) pmm[lid] = make_float2(bmin, red[0]);
}

// ---------------- reduce 8192 per-block partials -> mm (no atomics) ----------------
__global__ __launch_bounds__(256) void k_redmm(const float2* __restrict__ pmm,
                                               float* __restrict__ mm) {
  const int t = threadIdx.x;
  float mn = FINF, mx = -FINF;
  for (int i = t; i < 8192; i += 256) {
    const float2 v = pmm[i];
    mn = fminf(mn, v.x);
    mx = fmaxf(mx, v.y);
  }
  __shared__ float rmn[256], rmx[256];
  rmn[t] = mn; rmx[t] = mx;
  __syncthreads();
  for (int off = 128; off > 0; off >>= 1) {
    if (t < off) {
      rmn[t] = fminf(rmn[t], rmn[t + off]);
      rmx[t] = fmaxf(rmx[t], rmx[t + off]);
    }
    __syncthreads();
  }
  if (t == 0) { mm[0] = rmn[0]; mm[1] = rmx[0]; }
}

// ---------------- global normalize ----------------
__global__ void k_norm(float* __restrict__ out, const float* __restrict__ mm) {
  const float mn = mm[0];
  const float sc = 1.f / (mm[1] - mn);
  const int total4 = 16 * 3 * 262144 / 4;
  for (int i = blockIdx.x * 256 + threadIdx.x; i < total4; i += gridDim.x * 256) {
    float4 v = ((float4*)out)[i];
    v.x = (v.x - mn) * sc;
    v.y = (v.y - mn) * sc;
    v.z = (v.z - mn) * sc;
    v.w = (v.w - mn) * sc;
    ((float4*)out)[i] = v;
  }
}

extern "C" void kernel_launch(void* const* d_in, const int* in_sizes, int n_in,
                              void* d_out, int out_size, void* d_ws, size_t ws_size,
                              hipStream_t stream) {
  const float* x   = (const float*)d_in[0];
  const float* lat = (const float*)d_in[1];
  const float* w1  = (const float*)d_in[2];
  const float* b1  = (const float*)d_in[3];
  const float* w2  = (const float*)d_in[4];
  const float* b2  = (const float*)d_in[5];
  const float* w3  = (const float*)d_in[6];
  const float* b3  = (const float*)d_in[7];
  float* out = (float*)d_out;

  char* ws = (char*)d_ws;
  size_t off = 0;
  auto alloc = [&](size_t sz) -> void* {
    off = (off + 255) & ~(size_t)255;
    void* p = ws + off;
    off += sz;
    return p;
  };
  // One 16 MB region time-shared: h1part (conv) -> dc (hist/collect) -> dcH (dch/final).
  // Live ranges are strictly sequential in-stream.
  float*    big   = (float*)alloc((size_t)16 * 512 * 512 * sizeof(float));
  float*    h1p   = big;
  float*    dc    = big;
  float*    dcH   = big;
  float*    h1    = (float*)alloc(524288 * sizeof(float));
  float*    wt    = (float*)alloc(294912 * sizeof(float));
  float*    paramsp = (float*)alloc(16 * sizeof(float));
  unsigned* hist  = (unsigned*)alloc(16 * 4096 * sizeof(unsigned));
  int*      Bbin  = (int*)alloc(16 * sizeof(int));
  int*      rneed = (int*)alloc(16 * sizeof(int));
  int*      cnt   = (int*)alloc(16 * sizeof(int));
  float*    bsums = (float*)alloc(16 * 32 * 3 * sizeof(float));
  float*    candv = (float*)alloc(16 * 4096 * sizeof(float));
  int*      candi = (int*)alloc(16 * 4096 * sizeof(int));
  float*    Av    = (float*)alloc(16 * 3 * sizeof(float));
  float2*   pmm   = (float2*)alloc(8192 * sizeof(float2));
  float*    mm    = (float*)alloc(2 * sizeof(float));

  k_init<<<256, 256, 0, stream>>>(hist, cnt);
  k_wt<<<1152, 256, 0, stream>>>(w1, wt);
  k_conv1<<<dim3(16, 16, 8), 256, 0, stream>>>(lat, wt, h1p);
  k_combine<<<512, 256, 0, stream>>>(h1p, h1, b1);
  k_conv2<<<16, 256, 0, stream>>>(h1, w2, b2, w3, b3, paramsp);
  k_hist<<<dim3(32, 16), 256, 0, stream>>>(x, hist, dc);
  k_scan<<<16, 256, 0, stream>>>(hist, Bbin, rneed);
  k_collect<<<dim3(32, 16), 256, 0, stream>>>(x, dc, Bbin, cnt, candv, candi, bsums);
  k_finalA<<<16, 64, 0, stream>>>(x, bsums, cnt, rneed, candv, candi, Av);
  k_dch<<<dim3(512, 16), 256, 0, stream>>>(x, Av, dcH);
  k_final<<<dim3(512, 16), 256, 0, stream>>>(x, dcH, paramsp, Av, out, pmm);
  k_redmm<<<1, 256, 0, stream>>>(pmm, mm);
  k_norm<<<4096, 256, 0, stream>>>(out, mm);
}

// Round 6
// 192.763 us; speedup vs baseline: 1.5526x; 1.5526x over previous
//
#include <hip/hip_runtime.h>
#include <math.h>

#define FINF 3.0e38f

// ---------------- init small scratch ----------------
__global__ void k_init(unsigned* __restrict__ hist, int* __restrict__ cnt) {
  int i = blockIdx.x * 256 + threadIdx.x;
  if (i < 16 * 4096) hist[i] = 0u;
  if (i < 16) cnt[i] = 0;
}

// ---------------- transpose W1 (128,256,3,3) -> wt[ic][tap][oc] ----------------
__global__ void k_wt(const float* __restrict__ w1, float* __restrict__ wt) {
  const int idx = blockIdx.x * 256 + threadIdx.x;  // 294912 = 256*9*128
  if (idx >= 294912) return;
  const int oc = idx & 127;
  const int r = idx >> 7;
  const int tap = r % 9;
  const int ic = r / 9;
  wt[idx] = w1[((size_t)oc * 256 + ic) * 9 + tap];
}

// ---------------- conv1 (EXACT round-3 form: 63us known-good; do not "improve") ----------------
// grid (16 b, 16 ocg, 8 ks), block 256 (one output pixel each), 8 oc per thread, 32 ic per block
__global__ __launch_bounds__(256) void k_conv1(const float* __restrict__ lat,
                                               const float* __restrict__ wt,
                                               float* __restrict__ h1part) {
  const int b = blockIdx.x;
  const int ocg = blockIdx.y;
  const int ks = blockIdx.z;
  const int t = threadIdx.x;
  const int oy = t >> 4, ox = t & 15;
  __shared__ float sIn[4 * 1024];  // 4 channels x 32x32 = 16 KB
  float acc[8];
#pragma unroll
  for (int j = 0; j < 8; ++j) acc[j] = 0.f;
  const int ocb = ocg * 8;
  const int icb = ks * 32;
#pragma unroll 1
  for (int cc = 0; cc < 8; ++cc) {
    const int ic0 = icb + cc * 4;
    const float4* src = (const float4*)lat + ((size_t)b * 256 + ic0) * 256;
    __syncthreads();
#pragma unroll
    for (int ch = 0; ch < 4; ++ch) ((float4*)sIn)[ch * 256 + t] = src[ch * 256 + t];
    __syncthreads();
#pragma unroll
    for (int ic = 0; ic < 4; ++ic) {
      const float* ib = sIn + ic * 1024;
      const float* wp = wt + (size_t)(ic0 + ic) * 1152 + ocb;
#pragma unroll
      for (int ky = 0; ky < 3; ++ky) {
        const int iy = 2 * oy - 1 + ky;
        if (iy < 0) continue;
#pragma unroll
        for (int kx = 0; kx < 3; ++kx) {
          const int ix = 2 * ox - 1 + kx;
          if (ix < 0) continue;
          const float v = ib[iy * 32 + ix];
          const float* w8 = wp + (ky * 3 + kx) * 128;
          const float4 wa = *(const float4*)(w8);
          const float4 wb = *(const float4*)(w8 + 4);
          acc[0] = fmaf(wa.x, v, acc[0]);
          acc[1] = fmaf(wa.y, v, acc[1]);
          acc[2] = fmaf(wa.z, v, acc[2]);
          acc[3] = fmaf(wa.w, v, acc[3]);
          acc[4] = fmaf(wb.x, v, acc[4]);
          acc[5] = fmaf(wb.y, v, acc[5]);
          acc[6] = fmaf(wb.z, v, acc[6]);
          acc[7] = fmaf(wb.w, v, acc[7]);
        }
      }
    }
  }
  float* dst = h1part + (size_t)ks * 524288 + ((size_t)b * 128 + ocb) * 256 + t;
#pragma unroll
  for (int j = 0; j < 8; ++j) dst[j * 256] = acc[j];
}

// ---------------- combine 8 ksplit partials + bias + leaky ----------------
__global__ void k_combine(const float* __restrict__ h1p, float* __restrict__ h1,
                          const float* __restrict__ b1) {
  const int i = blockIdx.x * 256 + threadIdx.x;  // float4 index, 131072 total
  const float4* p = (const float4*)h1p;
  float4 a = p[i];
#pragma unroll
  for (int ks = 1; ks < 8; ++ks) {
    const float4 q = p[(size_t)ks * 131072 + i];
    a.x += q.x; a.y += q.y; a.z += q.z; a.w += q.w;
  }
  const int oc = (i >> 6) & 127;
  const float bias = b1[oc];
  float s;
  s = a.x + bias; a.x = s >= 0.f ? s : 0.02f * s;
  s = a.y + bias; a.y = s >= 0.f ? s : 0.02f * s;
  s = a.z + bias; a.z = s >= 0.f ? s : 0.02f * s;
  s = a.w + bias; a.w = s >= 0.f ? s : 0.02f * s;
  ((float4*)h1)[i] = a;
}

// ---------------- conv2 + mean + 1x1 conv + tanh -> params[b] ----------------
__global__ __launch_bounds__(256) void k_conv2(const float* __restrict__ h1,
                                               const float* __restrict__ w2,
                                               const float* __restrict__ b2,
                                               const float* __restrict__ w3,
                                               const float* __restrict__ b3,
                                               float* __restrict__ params) {
  const int b = blockIdx.x;
  const int t = threadIdx.x;
  __shared__ float sW[1152];
  __shared__ float red[256];
  for (int i = t; i < 1152; i += 256) sW[i] = w2[i];
  __syncthreads();
  const int pix = t >> 2, icq = t & 3;
  const int oy = pix >> 3, ox = pix & 7;
  const float* hb = h1 + (size_t)b * 128 * 256;
  float s = 0.f;
  for (int ic = icq * 32; ic < icq * 32 + 32; ++ic) {
    const float* hp = hb + ic * 256;
#pragma unroll
    for (int ky = 0; ky < 3; ++ky) {
      const int iy = 2 * oy - 1 + ky;
      if (iy < 0) continue;
#pragma unroll
      for (int kx = 0; kx < 3; ++kx) {
        const int ix = 2 * ox - 1 + kx;
        if (ix < 0) continue;
        s += sW[ic * 9 + ky * 3 + kx] * hp[iy * 16 + ix];
      }
    }
  }
  red[t] = s;
  __syncthreads();
  for (int off = 128; off > 0; off >>= 1) {
    if (t < off) red[t] += red[t + off];
    __syncthreads();
  }
  if (t == 0) {
    const float mean = red[0] / 64.f + b2[0];
    const float h = w3[0] * mean + b3[0];
    params[b] = tanhf(h) * 0.5f + 0.5f;
  }
}

// ---------------- histogram of dark channel (also writes dc); XCD-pinned per image ----------------
__global__ __launch_bounds__(256) void k_hist(const float* __restrict__ x,
                                              unsigned* __restrict__ ghist,
                                              float* __restrict__ dc) {
  // 512 blocks; map so image b's 32 blocks all sit on XCD (b&7): dc stays L2-local for k_collect
  const int lid = blockIdx.x;
  const int b = (lid & 7) | (((lid >> 3) & 1) << 3);
  const int blk = lid >> 4;
  const int t = threadIdx.x;
  __shared__ unsigned lh[4096];
  for (int i = t; i < 4096; i += 256) lh[i] = 0u;
  __syncthreads();
  const float* xr = x + (size_t)b * 3 * 262144;
  const float* xg = xr + 262144;
  const float* xb = xg + 262144;
  float4* dcb = (float4*)(dc + (size_t)b * 262144);
  const int f0 = blk * 2048;
#pragma unroll
  for (int i = 0; i < 8; ++i) {
    const int f4 = f0 + t + i * 256;
    const float4 r = ((const float4*)xr)[f4];
    const float4 g = ((const float4*)xg)[f4];
    const float4 bl = ((const float4*)xb)[f4];
    float4 d4;
    d4.x = fminf(fminf(r.x, g.x), bl.x); atomicAdd(&lh[min(4095, (int)(d4.x * 4096.f))], 1u);
    d4.y = fminf(fminf(r.y, g.y), bl.y); atomicAdd(&lh[min(4095, (int)(d4.y * 4096.f))], 1u);
    d4.z = fminf(fminf(r.z, g.z), bl.z); atomicAdd(&lh[min(4095, (int)(d4.z * 4096.f))], 1u);
    d4.w = fminf(fminf(r.w, g.w), bl.w); atomicAdd(&lh[min(4095, (int)(d4.w * 4096.f))], 1u);
    dcb[f4] = d4;
  }
  __syncthreads();
  for (int i = t; i < 4096; i += 256)
    if (lh[i]) atomicAdd(&ghist[b * 4096 + i], lh[i]);
}

// ---------------- suffix scan from top to find threshold bin ----------------
__global__ __launch_bounds__(256) void k_scan(const unsigned* __restrict__ ghist,
                                              int* __restrict__ Bbin, int* __restrict__ rneed) {
  const int b = blockIdx.x, t = threadIdx.x;
  __shared__ unsigned h[4096];
  __shared__ unsigned csum[256];
  for (int i = t; i < 4096; i += 256) h[i] = ghist[b * 4096 + i];
  __syncthreads();
  const int top = 4095 - 16 * t;
  unsigned s = 0;
#pragma unroll
  for (int k = 0; k < 16; ++k) s += h[top - k];
  csum[t] = s;
  __syncthreads();
  for (int off = 1; off < 256; off <<= 1) {
    const unsigned add = (t >= off) ? csum[t - off] : 0u;
    __syncthreads();
    csum[t] += add;
    __syncthreads();
  }
  const unsigned incl = csum[t];
  const unsigned before = incl - s;
  if (before < 262u && incl >= 262u) {
    unsigned cum = before;
    for (int k = 0; k < 16; ++k) {
      const unsigned c = h[top - k];
      if (cum + c >= 262u) { Bbin[b] = top - k; rneed[b] = (int)(262u - cum); break; }
      cum += c;
    }
  }
}

// ---------------- collect: reads dc (L2-local); sparse RGB fetches ----------------
__global__ __launch_bounds__(256) void k_collect(const float* __restrict__ x,
                                                 const float* __restrict__ dc,
                                                 const int* __restrict__ Bbin,
                                                 int* __restrict__ cnt,
                                                 float* __restrict__ candv,
                                                 int* __restrict__ candi,
                                                 float* __restrict__ bsums) {
  const int lid = blockIdx.x;  // same mapping as k_hist
  const int b = (lid & 7) | (((lid >> 3) & 1) << 3);
  const int blk = lid >> 4;
  const int t = threadIdx.x;
  const int B = Bbin[b];
  const float* xr = x + (size_t)b * 3 * 262144;
  const float* xg = xr + 262144;
  const float* xb = xg + 262144;
  const float4* dcb = (const float4*)(dc + (size_t)b * 262144);
  const int f0 = blk * 2048;
  float s0 = 0.f, s1 = 0.f, s2 = 0.f;
#pragma unroll
  for (int i = 0; i < 8; ++i) {
    const int f4 = f0 + t + i * 256;
    const float4 d4 = dcb[f4];
    const float dv[4] = {d4.x, d4.y, d4.z, d4.w};
#pragma unroll
    for (int j = 0; j < 4; ++j) {
      const int bin = min(4095, (int)(dv[j] * 4096.f));
      if (bin >= B) {
        const int idx = f4 * 4 + j;
        if (bin > B) {
          s0 += xr[idx]; s1 += xg[idx]; s2 += xb[idx];
        } else {
          const int k = atomicAdd(&cnt[b], 1);
          if (k < 4096) { candv[b * 4096 + k] = dv[j]; candi[b * 4096 + k] = idx; }
        }
      }
    }
  }
  __shared__ float red[256];
  red[t] = s0; __syncthreads();
  for (int off = 128; off > 0; off >>= 1) { if (t < off) red[t] += red[t + off]; __syncthreads(); }
  if (t == 0) bsums[((size_t)b * 32 + blk) * 3 + 0] = red[0];
  __syncthreads();
  red[t] = s1; __syncthreads();
  for (int off = 128; off > 0; off >>= 1) { if (t < off) red[t] += red[t + off]; __syncthreads(); }
  if (t == 0) bsums[((size_t)b * 32 + blk) * 3 + 1] = red[0];
  __syncthreads();
  red[t] = s2; __syncthreads();
  for (int off = 128; off > 0; off >>= 1) { if (t < off) red[t] += red[t + off]; __syncthreads(); }
  if (t == 0) bsums[((size_t)b * 32 + blk) * 3 + 2] = red[0];
}

// ---------------- finalize A (deterministic; tie-break value desc, index asc) ----------------
__global__ void k_finalA(const float* __restrict__ x, const float* __restrict__ bsums,
                         const int* __restrict__ cnt, const int* __restrict__ rneed,
                         float* __restrict__ candv, const int* __restrict__ candi,
                         float* __restrict__ Av) {
  const int b = blockIdx.x;
  if (threadIdx.x != 0) return;
  float S0 = 0.f, S1 = 0.f, S2 = 0.f;
  for (int k = 0; k < 32; ++k) {
    S0 += bsums[((size_t)b * 32 + k) * 3 + 0];
    S1 += bsums[((size_t)b * 32 + k) * 3 + 1];
    S2 += bsums[((size_t)b * 32 + k) * 3 + 2];
  }
  const int n = min(cnt[b], 4096);
  const int r = rneed[b];
  const float* xr = x + (size_t)b * 3 * 262144;
  const float* xg = xr + 262144;
  const float* xb = xg + 262144;
  for (int sel = 0; sel < r; ++sel) {
    int best = -1; float bv = -1.f; int bi = 0x7FFFFFFF;
    for (int i = 0; i < n; ++i) {
      const float v = candv[b * 4096 + i];
      const int id = candi[b * 4096 + i];
      if (v > bv || (v == bv && id < bi)) { best = i; bv = v; bi = id; }
    }
    if (best < 0) break;
    candv[b * 4096 + best] = -1.f;
    S0 += xr[bi]; S1 += xg[bi]; S2 += xb[bi];
  }
  Av[b * 3 + 0] = S0 / 262.f;
  Av[b * 3 + 1] = S1 / 262.f;
  Av[b * 3 + 2] = S2 / 262.f;
}

// ---------------- fused dc2 + 7x7 min-pool + out-minmax (no out write) ----------------
// 1024 blocks = 16 images x 64 tiles of 8 rows. Pipelined: hmin row i staged, row i-6 consumed.
// Phase-B x re-reads hit L1/L2 (touched 3 iterations earlier). Writes vm map + per-block minmax.
__global__ __launch_bounds__(256) void k_dchv(const float* __restrict__ x,
                                              const float* __restrict__ Av,
                                              const float* __restrict__ params,
                                              float* __restrict__ vm,
                                              float2* __restrict__ pmm) {
  const int lid = blockIdx.x;
  const int swz = (lid & 7) * 128 + (lid >> 3);  // XCD-chunked: image b -> XCD (b>>1)
  const int b = swz >> 6;
  const int y0 = (swz & 63) * 8;
  const int t = threadIdx.x;
  __shared__ float hmin[14][512];
  __shared__ float dcrow[520];
  const float a0 = Av[b * 3 + 0], a1 = Av[b * 3 + 1], a2 = Av[b * 3 + 2];
  const float pb = params[b];
  const float* xb = x + (size_t)b * 3 * 262144;
  float* vmb = vm + (size_t)b * 262144;
  float lmin = FINF, lmax = -FINF;
#pragma unroll 1
  for (int i = 0; i < 14; ++i) {
    const int row = y0 - 3 + i;
    const bool valid = (row >= 0) && (row < 512);
    if (valid) {
      const float2 r = ((const float2*)(xb + (size_t)row * 512))[t];
      const float2 g = ((const float2*)(xb + 262144 + (size_t)row * 512))[t];
      const float2 bl = ((const float2*)(xb + 524288 + (size_t)row * 512))[t];
      dcrow[3 + 2 * t]     = fminf(fminf(r.x / a0, g.x / a1), bl.x / a2);
      dcrow[3 + 2 * t + 1] = fminf(fminf(r.y / a0, g.y / a1), bl.y / a2);
      if (t < 3) { dcrow[t] = FINF; dcrow[515 + t] = FINF; }
    }
    __syncthreads();
    if (valid) {
      float m0 = dcrow[2 * t], m1 = dcrow[2 * t + 1];
#pragma unroll
      for (int k = 1; k < 7; ++k) {
        m0 = fminf(m0, dcrow[2 * t + k]);
        m1 = fminf(m1, dcrow[2 * t + 1 + k]);
      }
      hmin[i][2 * t] = m0;
      hmin[i][2 * t + 1] = m1;
    } else {
      hmin[i][2 * t] = FINF;
      hmin[i][2 * t + 1] = FINF;
    }
    __syncthreads();
    if (i >= 6) {
      const int j = i - 6;
      const int y = y0 + j;
      float2 v = ((const float2*)hmin[j])[t];
#pragma unroll
      for (int k = 1; k < 7; ++k) {
        const float2 h2 = ((const float2*)hmin[j + k])[t];
        v.x = fminf(v.x, h2.x);
        v.y = fminf(v.y, h2.y);
      }
      ((float2*)(vmb + (size_t)y * 512))[t] = v;
      const float T0 = fmaxf(1.f - pb * v.x, 0.01f);
      const float T1 = fmaxf(1.f - pb * v.y, 0.01f);
      const float i0 = 1.f / T0;
      const float i1 = 1.f / T1;
#pragma unroll
      for (int c = 0; c < 3; ++c) {
        const float a = (c == 0) ? a0 : ((c == 1) ? a1 : a2);
        const float2 xv = ((const float2*)(xb + (size_t)c * 262144 + (size_t)y * 512))[t];
        const float o0 = fmaf(xv.x - a, i0, a);
        const float o1 = fmaf(xv.y - a, i1, a);
        lmin = fminf(lmin, fminf(o0, o1));
        lmax = fmaxf(lmax, fmaxf(o0, o1));
      }
    }
  }
  __shared__ float red[256];
  red[t] = lmin; __syncthreads();
  for (int off = 128; off > 0; off >>= 1) { if (t < off) red[t] = fminf(red[t], red[t + off]); __syncthreads(); }
  const float bmin = red[0];
  __syncthreads();
  red[t] = lmax; __syncthreads();
  for (int off = 128; off > 0; off >>= 1) { if (t < off) red[t] = fmaxf(red[t], red[t + off]); __syncthreads(); }
  if (t == 0) pmm[lid] = make_float2(bmin, red[0]);
}

// ---------------- reduce 1024 per-block partials -> mm ----------------
__global__ __launch_bounds__(256) void k_redmm(const float2* __restrict__ pmm,
                                               float* __restrict__ mm) {
  const int t = threadIdx.x;
  float mn = FINF, mx = -FINF;
  for (int i = t; i < 1024; i += 256) {
    const float2 v = pmm[i];
    mn = fminf(mn, v.x);
    mx = fmaxf(mx, v.y);
  }
  __shared__ float rmn[256], rmx[256];
  rmn[t] = mn; rmx[t] = mx;
  __syncthreads();
  for (int off = 128; off > 0; off >>= 1) {
    if (t < off) {
      rmn[t] = fminf(rmn[t], rmn[t + off]);
      rmx[t] = fmaxf(rmx[t], rmx[t + off]);
    }
    __syncthreads();
  }
  if (t == 0) { mm[0] = rmn[0]; mm[1] = rmx[0]; }
}

// ---------------- final pass: recompute out from x + vm (identical exprs), normalize, write ----------------
__global__ __launch_bounds__(256) void k_norm2(const float* __restrict__ x,
                                               const float* __restrict__ vm,
                                               const float* __restrict__ params,
                                               const float* __restrict__ Av,
                                               const float* __restrict__ mm,
                                               float* __restrict__ out) {
  const int lid = blockIdx.y * gridDim.x + blockIdx.x;   // 8192
  const int swz = (lid & 7) * 1024 + (lid >> 3);         // image b -> XCD (b>>1): vm is L2-local
  const int y = swz & 511, b = swz >> 9;
  const int t = threadIdx.x;
  const float pb = params[b];
  const float a0 = Av[b * 3 + 0], a1 = Av[b * 3 + 1], a2 = Av[b * 3 + 2];
  const float mn = mm[0];
  const float sc = 1.f / (mm[1] - mn);
  const float2 v = ((const float2*)(vm + (size_t)b * 262144 + (size_t)y * 512))[t];
  const float T0 = fmaxf(1.f - pb * v.x, 0.01f);
  const float T1 = fmaxf(1.f - pb * v.y, 0.01f);
  const float i0 = 1.f / T0;
  const float i1 = 1.f / T1;
  const size_t rowoff = (size_t)b * 3 * 262144 + (size_t)y * 512;
#pragma unroll
  for (int c = 0; c < 3; ++c) {
    const float a = (c == 0) ? a0 : ((c == 1) ? a1 : a2);
    const float2 xv = ((const float2*)(x + rowoff + (size_t)c * 262144))[t];
    const float o0 = fmaf(xv.x - a, i0, a);
    const float o1 = fmaf(xv.y - a, i1, a);
    ((float2*)(out + rowoff + (size_t)c * 262144))[t] =
        make_float2((o0 - mn) * sc, (o1 - mn) * sc);
  }
}

extern "C" void kernel_launch(void* const* d_in, const int* in_sizes, int n_in,
                              void* d_out, int out_size, void* d_ws, size_t ws_size,
                              hipStream_t stream) {
  const float* x   = (const float*)d_in[0];
  const float* lat = (const float*)d_in[1];
  const float* w1  = (const float*)d_in[2];
  const float* b1  = (const float*)d_in[3];
  const float* w2  = (const float*)d_in[4];
  const float* b2  = (const float*)d_in[5];
  const float* w3  = (const float*)d_in[6];
  const float* b3  = (const float*)d_in[7];
  float* out = (float*)d_out;

  char* ws = (char*)d_ws;
  size_t off = 0;
  auto alloc = [&](size_t sz) -> void* {
    off = (off + 255) & ~(size_t)255;
    void* p = ws + off;
    off += sz;
    return p;
  };
  // One 16 MB region time-shared: h1part (conv) -> dc (hist/collect) -> vm (dchv/norm2).
  // Live ranges are strictly sequential in-stream.
  float*    big   = (float*)alloc((size_t)16 * 512 * 512 * sizeof(float));
  float*    h1p   = big;
  float*    dc    = big;
  float*    vmm   = big;
  float*    h1    = (float*)alloc(524288 * sizeof(float));
  float*    wt    = (float*)alloc(294912 * sizeof(float));
  float*    paramsp = (float*)alloc(16 * sizeof(float));
  unsigned* hist  = (unsigned*)alloc(16 * 4096 * sizeof(unsigned));
  int*      Bbin  = (int*)alloc(16 * sizeof(int));
  int*      rneed = (int*)alloc(16 * sizeof(int));
  int*      cnt   = (int*)alloc(16 * sizeof(int));
  float*    bsums = (float*)alloc(16 * 32 * 3 * sizeof(float));
  float*    candv = (float*)alloc(16 * 4096 * sizeof(float));
  int*      candi = (int*)alloc(16 * 4096 * sizeof(int));
  float*    Av    = (float*)alloc(16 * 3 * sizeof(float));
  float2*   pmm   = (float2*)alloc(1024 * sizeof(float2));
  float*    mm    = (float*)alloc(2 * sizeof(float));

  k_init<<<256, 256, 0, stream>>>(hist, cnt);
  k_wt<<<1152, 256, 0, stream>>>(w1, wt);
  k_conv1<<<dim3(16, 16, 8), 256, 0, stream>>>(lat, wt, h1p);
  k_combine<<<512, 256, 0, stream>>>(h1p, h1, b1);
  k_conv2<<<16, 256, 0, stream>>>(h1, w2, b2, w3, b3, paramsp);
  k_hist<<<512, 256, 0, stream>>>(x, hist, dc);
  k_scan<<<16, 256, 0, stream>>>(hist, Bbin, rneed);
  k_collect<<<512, 256, 0, stream>>>(x, dc, Bbin, cnt, candv, candi, bsums);
  k_finalA<<<16, 64, 0, stream>>>(x, bsums, cnt, rneed, candv, candi, Av);
  k_dchv<<<1024, 256, 0, stream>>>(x, Av, paramsp, vmm, pmm);
  k_redmm<<<1, 256, 0, stream>>>(pmm, mm);
  k_norm2<<<dim3(512, 16), 256, 0, stream>>>(x, vmm, paramsp, Av, mm, out);
}

// Round 7
// 146.729 us; speedup vs baseline: 2.0397x; 1.3137x over previous
//
#include <hip/hip_runtime.h>
#include <math.h>

#define FINF 3.0e38f

typedef __attribute__((ext_vector_type(8))) short short8v;   // 8 bf16 (4 VGPRs)
typedef __attribute__((ext_vector_type(4))) float float4v;   // MFMA acc

__device__ __forceinline__ unsigned short f2bf(float f) {
  unsigned u = __float_as_uint(f);
  unsigned r = u + 0x7FFFu + ((u >> 16) & 1u);  // RNE
  return (unsigned short)(r >> 16);
}

// ---------------- init small scratch ----------------
__global__ void k_init(unsigned* __restrict__ hist, int* __restrict__ cnt) {
  int i = blockIdx.x * 256 + threadIdx.x;
  if (i < 16 * 4096) hist[i] = 0u;
  if (i < 16) cnt[i] = 0;
}

// ---------------- W1 (128,256,3,3) -> bf16 wt2[tap][oc][ic] ----------------
__global__ void k_wt2(const float* __restrict__ w1, unsigned short* __restrict__ wt2) {
  const int idx = blockIdx.x * 256 + threadIdx.x;  // 294912 = 9*128*256
  if (idx >= 294912) return;
  const int ic = idx & 255;
  const int r = idx >> 8;
  const int oc = r & 127;
  const int tap = r >> 7;
  wt2[idx] = f2bf(w1[((size_t)oc * 256 + ic) * 9 + tap]);
}

// ---------------- conv1 via MFMA: per-tap GEMM D[oc][px] += W[oc][ic]*lat[ic][px'] ----------------
// grid (16 b, 8 ks, 2 oc-half), 512 thr = 8 waves (2 oc x 4 px). K-chunk = 32 ic x 9 taps.
// LDS: lat chunk bf16 transposed [px][ic], stride 40 (16B-aligned b128 reads), row 1024 = zeros
// for the pad gather (stride-2 conv => only iy<0 / ix<0 invalid).
__global__ __launch_bounds__(512) void k_conv1m(const float* __restrict__ lat,
                                                const unsigned short* __restrict__ wt2,
                                                float* __restrict__ h1part) {
  const int b = blockIdx.x, ks = blockIdx.y, nh = blockIdx.z;
  const int t = threadIdx.x;
  __shared__ unsigned short sA[1025 * 40];  // 82 KB
  {
    const float4* src = (const float4*)lat + ((size_t)b * 256 + ks * 32) * 256;
#pragma unroll
    for (int i = t; i < 8192; i += 512) {
      const int ic = i >> 8;
      const int q = i & 255;
      const float4 v = src[ic * 256 + q];
      const int px0 = q * 4;
      sA[(px0 + 0) * 40 + ic] = f2bf(v.x);
      sA[(px0 + 1) * 40 + ic] = f2bf(v.y);
      sA[(px0 + 2) * 40 + ic] = f2bf(v.z);
      sA[(px0 + 3) * 40 + ic] = f2bf(v.w);
    }
    if (t < 40) sA[1024 * 40 + t] = 0;
  }
  __syncthreads();

  const int lane = t & 63, wid = t >> 6;
  const int ocbase = nh * 64 + (wid & 1) * 32;
  const int pxbase = (wid >> 1) * 64;
  const int l15 = lane & 15, lg = lane >> 4;

  float4v acc[2][4];
#pragma unroll
  for (int f = 0; f < 2; ++f)
#pragma unroll
    for (int g = 0; g < 4; ++g) acc[f][g] = (float4v){0.f, 0.f, 0.f, 0.f};

#pragma unroll
  for (int tap = 0; tap < 9; ++tap) {
    const int ky = tap / 3, kx = tap % 3;
    short8v aW[2];
#pragma unroll
    for (int f = 0; f < 2; ++f) {
      const int oc = ocbase + f * 16 + l15;
      aW[f] = *(const short8v*)(wt2 + (size_t)(tap * 128 + oc) * 256 + ks * 32 + lg * 8);
    }
    short8v bL[4];
#pragma unroll
    for (int g = 0; g < 4; ++g) {
      const int px = pxbase + g * 16 + l15;
      const int iy = 2 * (px >> 4) - 1 + ky;
      const int ix = 2 * (px & 15) - 1 + kx;
      const int p = (iy >= 0 && ix >= 0) ? iy * 32 + ix : 1024;
      bL[g] = *(const short8v*)(sA + p * 40 + lg * 8);
    }
#pragma unroll
    for (int f = 0; f < 2; ++f)
#pragma unroll
      for (int g = 0; g < 4; ++g)
        acc[f][g] = __builtin_amdgcn_mfma_f32_16x16x32_bf16(aW[f], bL[g], acc[f][g], 0, 0, 0);
  }

  // D: col = lane&15 -> px, row = (lane>>4)*4 + r -> oc   [m89 layout]
  float* dst = h1part + (size_t)ks * 524288 + (size_t)b * 32768;
#pragma unroll
  for (int f = 0; f < 2; ++f)
#pragma unroll
    for (int g = 0; g < 4; ++g)
#pragma unroll
      for (int r = 0; r < 4; ++r) {
        const int oc = ocbase + f * 16 + lg * 4 + r;
        const int px = pxbase + g * 16 + l15;
        dst[oc * 256 + px] = acc[f][g][r];
      }
}

// ---------------- combine 8 ksplit partials + bias + leaky ----------------
__global__ void k_combine(const float* __restrict__ h1p, float* __restrict__ h1,
                          const float* __restrict__ b1) {
  const int i = blockIdx.x * 256 + threadIdx.x;  // float4 index, 131072 total
  const float4* p = (const float4*)h1p;
  float4 a = p[i];
#pragma unroll
  for (int ks = 1; ks < 8; ++ks) {
    const float4 q = p[(size_t)ks * 131072 + i];
    a.x += q.x; a.y += q.y; a.z += q.z; a.w += q.w;
  }
  const int oc = (i >> 6) & 127;
  const float bias = b1[oc];
  float s;
  s = a.x + bias; a.x = s >= 0.f ? s : 0.02f * s;
  s = a.y + bias; a.y = s >= 0.f ? s : 0.02f * s;
  s = a.z + bias; a.z = s >= 0.f ? s : 0.02f * s;
  s = a.w + bias; a.w = s >= 0.f ? s : 0.02f * s;
  ((float4*)h1)[i] = a;
}

// ---------------- conv2 + mean + 1x1 conv + tanh -> params[b] ----------------
__global__ __launch_bounds__(256) void k_conv2(const float* __restrict__ h1,
                                               const float* __restrict__ w2,
                                               const float* __restrict__ b2,
                                               const float* __restrict__ w3,
                                               const float* __restrict__ b3,
                                               float* __restrict__ params) {
  const int b = blockIdx.x;
  const int t = threadIdx.x;
  __shared__ float sW[1152];
  __shared__ float red[256];
  for (int i = t; i < 1152; i += 256) sW[i] = w2[i];
  __syncthreads();
  const int pix = t >> 2, icq = t & 3;
  const int oy = pix >> 3, ox = pix & 7;
  const float* hb = h1 + (size_t)b * 128 * 256;
  float s = 0.f;
  for (int ic = icq * 32; ic < icq * 32 + 32; ++ic) {
    const float* hp = hb + ic * 256;
#pragma unroll
    for (int ky = 0; ky < 3; ++ky) {
      const int iy = 2 * oy - 1 + ky;
      if (iy < 0) continue;
#pragma unroll
      for (int kx = 0; kx < 3; ++kx) {
        const int ix = 2 * ox - 1 + kx;
        if (ix < 0) continue;
        s += sW[ic * 9 + ky * 3 + kx] * hp[iy * 16 + ix];
      }
    }
  }
  red[t] = s;
  __syncthreads();
  for (int off = 128; off > 0; off >>= 1) {
    if (t < off) red[t] += red[t + off];
    __syncthreads();
  }
  if (t == 0) {
    const float mean = red[0] / 64.f + b2[0];
    const float h = w3[0] * mean + b3[0];
    params[b] = tanhf(h) * 0.5f + 0.5f;
  }
}

// ---------------- histogram of dark channel (also writes dc); XCD-pinned per image ----------------
__global__ __launch_bounds__(256) void k_hist(const float* __restrict__ x,
                                              unsigned* __restrict__ ghist,
                                              float* __restrict__ dc) {
  const int lid = blockIdx.x;
  const int b = (lid & 7) | (((lid >> 3) & 1) << 3);
  const int blk = lid >> 4;
  const int t = threadIdx.x;
  __shared__ unsigned lh[4096];
  for (int i = t; i < 4096; i += 256) lh[i] = 0u;
  __syncthreads();
  const float* xr = x + (size_t)b * 3 * 262144;
  const float* xg = xr + 262144;
  const float* xb = xg + 262144;
  float4* dcb = (float4*)(dc + (size_t)b * 262144);
  const int f0 = blk * 2048;
#pragma unroll
  for (int i = 0; i < 8; ++i) {
    const int f4 = f0 + t + i * 256;
    const float4 r = ((const float4*)xr)[f4];
    const float4 g = ((const float4*)xg)[f4];
    const float4 bl = ((const float4*)xb)[f4];
    float4 d4;
    d4.x = fminf(fminf(r.x, g.x), bl.x); atomicAdd(&lh[min(4095, (int)(d4.x * 4096.f))], 1u);
    d4.y = fminf(fminf(r.y, g.y), bl.y); atomicAdd(&lh[min(4095, (int)(d4.y * 4096.f))], 1u);
    d4.z = fminf(fminf(r.z, g.z), bl.z); atomicAdd(&lh[min(4095, (int)(d4.z * 4096.f))], 1u);
    d4.w = fminf(fminf(r.w, g.w), bl.w); atomicAdd(&lh[min(4095, (int)(d4.w * 4096.f))], 1u);
    dcb[f4] = d4;
  }
  __syncthreads();
  for (int i = t; i < 4096; i += 256)
    if (lh[i]) atomicAdd(&ghist[b * 4096 + i], lh[i]);
}

// ---------------- suffix scan from top to find threshold bin ----------------
__global__ __launch_bounds__(256) void k_scan(const unsigned* __restrict__ ghist,
                                              int* __restrict__ Bbin, int* __restrict__ rneed) {
  const int b = blockIdx.x, t = threadIdx.x;
  __shared__ unsigned h[4096];
  __shared__ unsigned csum[256];
  for (int i = t; i < 4096; i += 256) h[i] = ghist[b * 4096 + i];
  __syncthreads();
  const int top = 4095 - 16 * t;
  unsigned s = 0;
#pragma unroll
  for (int k = 0; k < 16; ++k) s += h[top - k];
  csum[t] = s;
  __syncthreads();
  for (int off = 1; off < 256; off <<= 1) {
    const unsigned add = (t >= off) ? csum[t - off] : 0u;
    __syncthreads();
    csum[t] += add;
    __syncthreads();
  }
  const unsigned incl = csum[t];
  const unsigned before = incl - s;
  if (before < 262u && incl >= 262u) {
    unsigned cum = before;
    for (int k = 0; k < 16; ++k) {
      const unsigned c = h[top - k];
      if (cum + c >= 262u) { Bbin[b] = top - k; rneed[b] = (int)(262u - cum); break; }
      cum += c;
    }
  }
}

// ---------------- collect: reads dc (L2-local); sparse RGB fetches ----------------
__global__ __launch_bounds__(256) void k_collect(const float* __restrict__ x,
                                                 const float* __restrict__ dc,
                                                 const int* __restrict__ Bbin,
                                                 int* __restrict__ cnt,
                                                 float* __restrict__ candv,
                                                 int* __restrict__ candi,
                                                 float* __restrict__ bsums) {
  const int lid = blockIdx.x;  // same mapping as k_hist
  const int b = (lid & 7) | (((lid >> 3) & 1) << 3);
  const int blk = lid >> 4;
  const int t = threadIdx.x;
  const int B = Bbin[b];
  const float* xr = x + (size_t)b * 3 * 262144;
  const float* xg = xr + 262144;
  const float* xb = xg + 262144;
  const float4* dcb = (const float4*)(dc + (size_t)b * 262144);
  const int f0 = blk * 2048;
  float s0 = 0.f, s1 = 0.f, s2 = 0.f;
#pragma unroll
  for (int i = 0; i < 8; ++i) {
    const int f4 = f0 + t + i * 256;
    const float4 d4 = dcb[f4];
    const float dv[4] = {d4.x, d4.y, d4.z, d4.w};
#pragma unroll
    for (int j = 0; j < 4; ++j) {
      const int bin = min(4095, (int)(dv[j] * 4096.f));
      if (bin >= B) {
        const int idx = f4 * 4 + j;
        if (bin > B) {
          s0 += xr[idx]; s1 += xg[idx]; s2 += xb[idx];
        } else {
          const int k = atomicAdd(&cnt[b], 1);
          if (k < 4096) { candv[b * 4096 + k] = dv[j]; candi[b * 4096 + k] = idx; }
        }
      }
    }
  }
  __shared__ float red[256];
  red[t] = s0; __syncthreads();
  for (int off = 128; off > 0; off >>= 1) { if (t < off) red[t] += red[t + off]; __syncthreads(); }
  if (t == 0) bsums[((size_t)b * 32 + blk) * 3 + 0] = red[0];
  __syncthreads();
  red[t] = s1; __syncthreads();
  for (int off = 128; off > 0; off >>= 1) { if (t < off) red[t] += red[t + off]; __syncthreads(); }
  if (t == 0) bsums[((size_t)b * 32 + blk) * 3 + 1] = red[0];
  __syncthreads();
  red[t] = s2; __syncthreads();
  for (int off = 128; off > 0; off >>= 1) { if (t < off) red[t] += red[t + off]; __syncthreads(); }
  if (t == 0) bsums[((size_t)b * 32 + blk) * 3 + 2] = red[0];
}

// ---------------- finalize A (deterministic; tie-break value desc, index asc) ----------------
__global__ void k_finalA(const float* __restrict__ x, const float* __restrict__ bsums,
                         const int* __restrict__ cnt, const int* __restrict__ rneed,
                         float* __restrict__ candv, const int* __restrict__ candi,
                         float* __restrict__ Av) {
  const int b = blockIdx.x;
  if (threadIdx.x != 0) return;
  float S0 = 0.f, S1 = 0.f, S2 = 0.f;
  for (int k = 0; k < 32; ++k) {
    S0 += bsums[((size_t)b * 32 + k) * 3 + 0];
    S1 += bsums[((size_t)b * 32 + k) * 3 + 1];
    S2 += bsums[((size_t)b * 32 + k) * 3 + 2];
  }
  const int n = min(cnt[b], 4096);
  const int r = rneed[b];
  const float* xr = x + (size_t)b * 3 * 262144;
  const float* xg = xr + 262144;
  const float* xb = xg + 262144;
  for (int sel = 0; sel < r; ++sel) {
    int best = -1; float bv = -1.f; int bi = 0x7FFFFFFF;
    for (int i = 0; i < n; ++i) {
      const float v = candv[b * 4096 + i];
      const int id = candi[b * 4096 + i];
      if (v > bv || (v == bv && id < bi)) { best = i; bv = v; bi = id; }
    }
    if (best < 0) break;
    candv[b * 4096 + best] = -1.f;
    S0 += xr[bi]; S1 += xg[bi]; S2 += xb[bi];
  }
  Av[b * 3 + 0] = S0 / 262.f;
  Av[b * 3 + 1] = S1 / 262.f;
  Av[b * 3 + 2] = S2 / 262.f;
}

// ---------------- fused dc2 + 7x7 min-pool + out-minmax (no out write) ----------------
__global__ __launch_bounds__(256) void k_dchv(const float* __restrict__ x,
                                              const float* __restrict__ Av,
                                              const float* __restrict__ params,
                                              float* __restrict__ vm,
                                              float2* __restrict__ pmm) {
  const int lid = blockIdx.x;
  const int swz = (lid & 7) * 128 + (lid >> 3);  // XCD-chunked: image b -> XCD (b>>1)
  const int b = swz >> 6;
  const int y0 = (swz & 63) * 8;
  const int t = threadIdx.x;
  __shared__ float hmin[14][512];
  __shared__ float dcrow[520];
  const float a0 = Av[b * 3 + 0], a1 = Av[b * 3 + 1], a2 = Av[b * 3 + 2];
  const float pb = params[b];
  const float* xb = x + (size_t)b * 3 * 262144;
  float* vmb = vm + (size_t)b * 262144;
  float lmin = FINF, lmax = -FINF;
#pragma unroll 1
  for (int i = 0; i < 14; ++i) {
    const int row = y0 - 3 + i;
    const bool valid = (row >= 0) && (row < 512);
    if (valid) {
      const float2 r = ((const float2*)(xb + (size_t)row * 512))[t];
      const float2 g = ((const float2*)(xb + 262144 + (size_t)row * 512))[t];
      const float2 bl = ((const float2*)(xb + 524288 + (size_t)row * 512))[t];
      dcrow[3 + 2 * t]     = fminf(fminf(r.x / a0, g.x / a1), bl.x / a2);
      dcrow[3 + 2 * t + 1] = fminf(fminf(r.y / a0, g.y / a1), bl.y / a2);
      if (t < 3) { dcrow[t] = FINF; dcrow[515 + t] = FINF; }
    }
    __syncthreads();
    if (valid) {
      float m0 = dcrow[2 * t], m1 = dcrow[2 * t + 1];
#pragma unroll
      for (int k = 1; k < 7; ++k) {
        m0 = fminf(m0, dcrow[2 * t + k]);
        m1 = fminf(m1, dcrow[2 * t + 1 + k]);
      }
      hmin[i][2 * t] = m0;
      hmin[i][2 * t + 1] = m1;
    } else {
      hmin[i][2 * t] = FINF;
      hmin[i][2 * t + 1] = FINF;
    }
    __syncthreads();
    if (i >= 6) {
      const int j = i - 6;
      const int y = y0 + j;
      float2 v = ((const float2*)hmin[j])[t];
#pragma unroll
      for (int k = 1; k < 7; ++k) {
        const float2 h2 = ((const float2*)hmin[j + k])[t];
        v.x = fminf(v.x, h2.x);
        v.y = fminf(v.y, h2.y);
      }
      ((float2*)(vmb + (size_t)y * 512))[t] = v;
      const float T0 = fmaxf(1.f - pb * v.x, 0.01f);
      const float T1 = fmaxf(1.f - pb * v.y, 0.01f);
      const float i0 = 1.f / T0;
      const float i1 = 1.f / T1;
#pragma unroll
      for (int c = 0; c < 3; ++c) {
        const float a = (c == 0) ? a0 : ((c == 1) ? a1 : a2);
        const float2 xv = ((const float2*)(xb + (size_t)c * 262144 + (size_t)y * 512))[t];
        const float o0 = fmaf(xv.x - a, i0, a);
        const float o1 = fmaf(xv.y - a, i1, a);
        lmin = fminf(lmin, fminf(o0, o1));
        lmax = fmaxf(lmax, fmaxf(o0, o1));
      }
    }
  }
  __shared__ float red[256];
  red[t] = lmin; __syncthreads();
  for (int off = 128; off > 0; off >>= 1) { if (t < off) red[t] = fminf(red[t], red[t + off]); __syncthreads(); }
  const float bmin = red[0];
  __syncthreads();
  red[t] = lmax; __syncthreads();
  for (int off = 128; off > 0; off >>= 1) { if (t < off) red[t] = fmaxf(red[t], red[t + off]); __syncthreads(); }
  if (t == 0) pmm[lid] = make_float2(bmin, red[0]);
}

// ---------------- reduce 1024 per-block partials -> mm ----------------
__global__ __launch_bounds__(256) void k_redmm(const float2* __restrict__ pmm,
                                               float* __restrict__ mm) {
  const int t = threadIdx.x;
  float mn = FINF, mx = -FINF;
  for (int i = t; i < 1024; i += 256) {
    const float2 v = pmm[i];
    mn = fminf(mn, v.x);
    mx = fmaxf(mx, v.y);
  }
  __shared__ float rmn[256], rmx[256];
  rmn[t] = mn; rmx[t] = mx;
  __syncthreads();
  for (int off = 128; off > 0; off >>= 1) {
    if (t < off) {
      rmn[t] = fminf(rmn[t], rmn[t + off]);
      rmx[t] = fmaxf(rmx[t], rmx[t + off]);
    }
    __syncthreads();
  }
  if (t == 0) { mm[0] = rmn[0]; mm[1] = rmx[0]; }
}

// ---------------- final pass: recompute out from x + vm (identical exprs), normalize, write ----------------
__global__ __launch_bounds__(256) void k_norm2(const float* __restrict__ x,
                                               const float* __restrict__ vm,
                                               const float* __restrict__ params,
                                               const float* __restrict__ Av,
                                               const float* __restrict__ mm,
                                               float* __restrict__ out) {
  const int lid = blockIdx.y * gridDim.x + blockIdx.x;   // 8192
  const int swz = (lid & 7) * 1024 + (lid >> 3);         // image b -> XCD (b>>1): vm is L2-local
  const int y = swz & 511, b = swz >> 9;
  const int t = threadIdx.x;
  const float pb = params[b];
  const float a0 = Av[b * 3 + 0], a1 = Av[b * 3 + 1], a2 = Av[b * 3 + 2];
  const float mn = mm[0];
  const float sc = 1.f / (mm[1] - mn);
  const float2 v = ((const float2*)(vm + (size_t)b * 262144 + (size_t)y * 512))[t];
  const float T0 = fmaxf(1.f - pb * v.x, 0.01f);
  const float T1 = fmaxf(1.f - pb * v.y, 0.01f);
  const float i0 = 1.f / T0;
  const float i1 = 1.f / T1;
  const size_t rowoff = (size_t)b * 3 * 262144 + (size_t)y * 512;
#pragma unroll
  for (int c = 0; c < 3; ++c) {
    const float a = (c == 0) ? a0 : ((c == 1) ? a1 : a2);
    const float2 xv = ((const float2*)(x + rowoff + (size_t)c * 262144))[t];
    const float o0 = fmaf(xv.x - a, i0, a);
    const float o1 = fmaf(xv.y - a, i1, a);
    ((float2*)(out + rowoff + (size_t)c * 262144))[t] =
        make_float2((o0 - mn) * sc, (o1 - mn) * sc);
  }
}

extern "C" void kernel_launch(void* const* d_in, const int* in_sizes, int n_in,
                              void* d_out, int out_size, void* d_ws, size_t ws_size,
                              hipStream_t stream) {
  const float* x   = (const float*)d_in[0];
  const float* lat = (const float*)d_in[1];
  const float* w1  = (const float*)d_in[2];
  const float* b1  = (const float*)d_in[3];
  const float* w2  = (const float*)d_in[4];
  const float* b2  = (const float*)d_in[5];
  const float* w3  = (const float*)d_in[6];
  const float* b3  = (const float*)d_in[7];
  float* out = (float*)d_out;

  char* ws = (char*)d_ws;
  size_t off = 0;
  auto alloc = [&](size_t sz) -> void* {
    off = (off + 255) & ~(size_t)255;
    void* p = ws + off;
    off += sz;
    return p;
  };
  // One 16 MB region time-shared: h1part (conv) -> dc (hist/collect) -> vm (dchv/norm2).
  float*    big   = (float*)alloc((size_t)16 * 512 * 512 * sizeof(float));
  float*    h1p   = big;
  float*    dc    = big;
  float*    vmm   = big;
  float*    h1    = (float*)alloc(524288 * sizeof(float));
  unsigned short* wt2 = (unsigned short*)alloc(294912 * sizeof(unsigned short));
  float*    paramsp = (float*)alloc(16 * sizeof(float));
  unsigned* hist  = (unsigned*)alloc(16 * 4096 * sizeof(unsigned));
  int*      Bbin  = (int*)alloc(16 * sizeof(int));
  int*      rneed = (int*)alloc(16 * sizeof(int));
  int*      cnt   = (int*)alloc(16 * sizeof(int));
  float*    bsums = (float*)alloc(16 * 32 * 3 * sizeof(float));
  float*    candv = (float*)alloc(16 * 4096 * sizeof(float));
  int*      candi = (int*)alloc(16 * 4096 * sizeof(int));
  float*    Av    = (float*)alloc(16 * 3 * sizeof(float));
  float2*   pmm   = (float2*)alloc(1024 * sizeof(float2));
  float*    mm    = (float*)alloc(2 * sizeof(float));

  k_init<<<256, 256, 0, stream>>>(hist, cnt);
  k_wt2<<<1152, 256, 0, stream>>>(w1, wt2);
  k_conv1m<<<dim3(16, 8, 2), 512, 0, stream>>>(lat, wt2, h1p);
  k_combine<<<512, 256, 0, stream>>>(h1p, h1, b1);
  k_conv2<<<16, 256, 0, stream>>>(h1, w2, b2, w3, b3, paramsp);
  k_hist<<<512, 256, 0, stream>>>(x, hist, dc);
  k_scan<<<16, 256, 0, stream>>>(hist, Bbin, rneed);
  k_collect<<<512, 256, 0, stream>>>(x, dc, Bbin, cnt, candv, candi, bsums);
  k_finalA<<<16, 64, 0, stream>>>(x, bsums, cnt, rneed, candv, candi, Av);
  k_dchv<<<1024, 256, 0, stream>>>(x, Av, paramsp, vmm, pmm);
  k_redmm<<<1, 256, 0, stream>>>(pmm, mm);
  k_norm2<<<dim3(512, 16), 256, 0, stream>>>(x, vmm, paramsp, Av, mm, out);
}

// Round 8
// 144.937 us; speedup vs baseline: 2.0649x; 1.0124x over previous
//
#include <hip/hip_runtime.h>
#include <math.h>

#define FINF 3.0e38f

typedef __attribute__((ext_vector_type(8))) short short8v;   // 8 bf16 (4 VGPRs)
typedef __attribute__((ext_vector_type(4))) float float4v;   // MFMA acc

__device__ __forceinline__ unsigned short f2bf(float f) {
  unsigned u = __float_as_uint(f);
  unsigned r = u + 0x7FFFu + ((u >> 16) & 1u);  // RNE
  return (unsigned short)(r >> 16);
}

// ---------------- prep: W1 -> bf16 wt2[tap][oc][ic]; zero hist/cnt ----------------
__global__ void k_prep(const float* __restrict__ w1, unsigned short* __restrict__ wt2,
                       unsigned* __restrict__ hist, int* __restrict__ cnt) {
  const int idx = blockIdx.x * 256 + threadIdx.x;  // 294912 = 9*128*256
  if (idx < 294912) {
    const int ic = idx & 255;
    const int r = idx >> 8;
    const int oc = r & 127;
    const int tap = r >> 7;
    wt2[idx] = f2bf(w1[((size_t)oc * 256 + ic) * 9 + tap]);
  }
  if (idx < 16 * 4096) hist[idx] = 0u;
  if (idx < 16) cnt[idx] = 0;
}

// ---------------- conv1 via MFMA (round-7 form, verified) ----------------
__global__ __launch_bounds__(512) void k_conv1m(const float* __restrict__ lat,
                                                const unsigned short* __restrict__ wt2,
                                                float* __restrict__ h1part) {
  const int b = blockIdx.x, ks = blockIdx.y, nh = blockIdx.z;
  const int t = threadIdx.x;
  __shared__ unsigned short sA[1025 * 40];  // 82 KB
  {
    const float4* src = (const float4*)lat + ((size_t)b * 256 + ks * 32) * 256;
#pragma unroll
    for (int i = t; i < 8192; i += 512) {
      const int ic = i >> 8;
      const int q = i & 255;
      const float4 v = src[ic * 256 + q];
      const int px0 = q * 4;
      sA[(px0 + 0) * 40 + ic] = f2bf(v.x);
      sA[(px0 + 1) * 40 + ic] = f2bf(v.y);
      sA[(px0 + 2) * 40 + ic] = f2bf(v.z);
      sA[(px0 + 3) * 40 + ic] = f2bf(v.w);
    }
    if (t < 40) sA[1024 * 40 + t] = 0;
  }
  __syncthreads();

  const int lane = t & 63, wid = t >> 6;
  const int ocbase = nh * 64 + (wid & 1) * 32;
  const int pxbase = (wid >> 1) * 64;
  const int l15 = lane & 15, lg = lane >> 4;

  float4v acc[2][4];
#pragma unroll
  for (int f = 0; f < 2; ++f)
#pragma unroll
    for (int g = 0; g < 4; ++g) acc[f][g] = (float4v){0.f, 0.f, 0.f, 0.f};

#pragma unroll
  for (int tap = 0; tap < 9; ++tap) {
    const int ky = tap / 3, kx = tap % 3;
    short8v aW[2];
#pragma unroll
    for (int f = 0; f < 2; ++f) {
      const int oc = ocbase + f * 16 + l15;
      aW[f] = *(const short8v*)(wt2 + (size_t)(tap * 128 + oc) * 256 + ks * 32 + lg * 8);
    }
    short8v bL[4];
#pragma unroll
    for (int g = 0; g < 4; ++g) {
      const int px = pxbase + g * 16 + l15;
      const int iy = 2 * (px >> 4) - 1 + ky;
      const int ix = 2 * (px & 15) - 1 + kx;
      const int p = (iy >= 0 && ix >= 0) ? iy * 32 + ix : 1024;
      bL[g] = *(const short8v*)(sA + p * 40 + lg * 8);
    }
#pragma unroll
    for (int f = 0; f < 2; ++f)
#pragma unroll
      for (int g = 0; g < 4; ++g)
        acc[f][g] = __builtin_amdgcn_mfma_f32_16x16x32_bf16(aW[f], bL[g], acc[f][g], 0, 0, 0);
  }

  float* dst = h1part + (size_t)ks * 524288 + (size_t)b * 32768;
#pragma unroll
  for (int f = 0; f < 2; ++f)
#pragma unroll
    for (int g = 0; g < 4; ++g)
#pragma unroll
      for (int r = 0; r < 4; ++r) {
        const int oc = ocbase + f * 16 + lg * 4 + r;
        const int px = pxbase + g * 16 + l15;
        dst[oc * 256 + px] = acc[f][g][r];
      }
}

// ---------------- combine 8 ksplit partials + bias + leaky ----------------
__global__ void k_combine(const float* __restrict__ h1p, float* __restrict__ h1,
                          const float* __restrict__ b1) {
  const int i = blockIdx.x * 256 + threadIdx.x;  // float4 index, 131072 total
  const float4* p = (const float4*)h1p;
  float4 a = p[i];
#pragma unroll
  for (int ks = 1; ks < 8; ++ks) {
    const float4 q = p[(size_t)ks * 131072 + i];
    a.x += q.x; a.y += q.y; a.z += q.z; a.w += q.w;
  }
  const int oc = (i >> 6) & 127;
  const float bias = b1[oc];
  float s;
  s = a.x + bias; a.x = s >= 0.f ? s : 0.02f * s;
  s = a.y + bias; a.y = s >= 0.f ? s : 0.02f * s;
  s = a.z + bias; a.z = s >= 0.f ? s : 0.02f * s;
  s = a.w + bias; a.w = s >= 0.f ? s : 0.02f * s;
  ((float4*)h1)[i] = a;
}

// ---------------- conv2 + mean + 1x1 conv + tanh -> params[b] ----------------
__global__ __launch_bounds__(256) void k_conv2(const float* __restrict__ h1,
                                               const float* __restrict__ w2,
                                               const float* __restrict__ b2,
                                               const float* __restrict__ w3,
                                               const float* __restrict__ b3,
                                               float* __restrict__ params) {
  const int b = blockIdx.x;
  const int t = threadIdx.x;
  __shared__ float sW[1152];
  __shared__ float red[256];
  for (int i = t; i < 1152; i += 256) sW[i] = w2[i];
  __syncthreads();
  const int pix = t >> 2, icq = t & 3;
  const int oy = pix >> 3, ox = pix & 7;
  const float* hb = h1 + (size_t)b * 128 * 256;
  float s = 0.f;
  for (int ic = icq * 32; ic < icq * 32 + 32; ++ic) {
    const float* hp = hb + ic * 256;
#pragma unroll
    for (int ky = 0; ky < 3; ++ky) {
      const int iy = 2 * oy - 1 + ky;
      if (iy < 0) continue;
#pragma unroll
      for (int kx = 0; kx < 3; ++kx) {
        const int ix = 2 * ox - 1 + kx;
        if (ix < 0) continue;
        s += sW[ic * 9 + ky * 3 + kx] * hp[iy * 16 + ix];
      }
    }
  }
  red[t] = s;
  __syncthreads();
  for (int off = 128; off > 0; off >>= 1) {
    if (t < off) red[t] += red[t + off];
    __syncthreads();
  }
  if (t == 0) {
    const float mean = red[0] / 64.f + b2[0];
    const float h = w3[0] * mean + b3[0];
    params[b] = tanhf(h) * 0.5f + 0.5f;
  }
}

// ---------------- histogram of dark channel (also writes dc); XCD-pinned per image ----------------
__global__ __launch_bounds__(256) void k_hist(const float* __restrict__ x,
                                              unsigned* __restrict__ ghist,
                                              float* __restrict__ dc) {
  const int lid = blockIdx.x;
  const int b = (lid & 7) | (((lid >> 3) & 1) << 3);
  const int blk = lid >> 4;
  const int t = threadIdx.x;
  __shared__ unsigned lh[4096];
  for (int i = t; i < 4096; i += 256) lh[i] = 0u;
  __syncthreads();
  const float* xr = x + (size_t)b * 3 * 262144;
  const float* xg = xr + 262144;
  const float* xb = xg + 262144;
  float4* dcb = (float4*)(dc + (size_t)b * 262144);
  const int f0 = blk * 2048;
#pragma unroll
  for (int i = 0; i < 8; ++i) {
    const int f4 = f0 + t + i * 256;
    const float4 r = ((const float4*)xr)[f4];
    const float4 g = ((const float4*)xg)[f4];
    const float4 bl = ((const float4*)xb)[f4];
    float4 d4;
    d4.x = fminf(fminf(r.x, g.x), bl.x); atomicAdd(&lh[min(4095, (int)(d4.x * 4096.f))], 1u);
    d4.y = fminf(fminf(r.y, g.y), bl.y); atomicAdd(&lh[min(4095, (int)(d4.y * 4096.f))], 1u);
    d4.z = fminf(fminf(r.z, g.z), bl.z); atomicAdd(&lh[min(4095, (int)(d4.z * 4096.f))], 1u);
    d4.w = fminf(fminf(r.w, g.w), bl.w); atomicAdd(&lh[min(4095, (int)(d4.w * 4096.f))], 1u);
    dcb[f4] = d4;
  }
  __syncthreads();
  for (int i = t; i < 4096; i += 256)
    if (lh[i]) atomicAdd(&ghist[b * 4096 + i], lh[i]);
}

// ---------------- suffix scan from top to find threshold bin ----------------
__global__ __launch_bounds__(256) void k_scan(const unsigned* __restrict__ ghist,
                                              int* __restrict__ Bbin, int* __restrict__ rneed) {
  const int b = blockIdx.x, t = threadIdx.x;
  __shared__ unsigned h[4096];
  __shared__ unsigned csum[256];
  for (int i = t; i < 4096; i += 256) h[i] = ghist[b * 4096 + i];
  __syncthreads();
  const int top = 4095 - 16 * t;
  unsigned s = 0;
#pragma unroll
  for (int k = 0; k < 16; ++k) s += h[top - k];
  csum[t] = s;
  __syncthreads();
  for (int off = 1; off < 256; off <<= 1) {
    const unsigned add = (t >= off) ? csum[t - off] : 0u;
    __syncthreads();
    csum[t] += add;
    __syncthreads();
  }
  const unsigned incl = csum[t];
  const unsigned before = incl - s;
  if (before < 262u && incl >= 262u) {
    unsigned cum = before;
    for (int k = 0; k < 16; ++k) {
      const unsigned c = h[top - k];
      if (cum + c >= 262u) { Bbin[b] = top - k; rneed[b] = (int)(262u - cum); break; }
      cum += c;
    }
  }
}

// ---------------- collect: reads dc (L2-local); sparse RGB fetches ----------------
__global__ __launch_bounds__(256) void k_collect(const float* __restrict__ x,
                                                 const float* __restrict__ dc,
                                                 const int* __restrict__ Bbin,
                                                 int* __restrict__ cnt,
                                                 float* __restrict__ candv,
                                                 int* __restrict__ candi,
                                                 float* __restrict__ bsums) {
  const int lid = blockIdx.x;  // same mapping as k_hist
  const int b = (lid & 7) | (((lid >> 3) & 1) << 3);
  const int blk = lid >> 4;
  const int t = threadIdx.x;
  const int B = Bbin[b];
  const float* xr = x + (size_t)b * 3 * 262144;
  const float* xg = xr + 262144;
  const float* xb = xg + 262144;
  const float4* dcb = (const float4*)(dc + (size_t)b * 262144);
  const int f0 = blk * 2048;
  float s0 = 0.f, s1 = 0.f, s2 = 0.f;
#pragma unroll
  for (int i = 0; i < 8; ++i) {
    const int f4 = f0 + t + i * 256;
    const float4 d4 = dcb[f4];
    const float dv[4] = {d4.x, d4.y, d4.z, d4.w};
#pragma unroll
    for (int j = 0; j < 4; ++j) {
      const int bin = min(4095, (int)(dv[j] * 4096.f));
      if (bin >= B) {
        const int idx = f4 * 4 + j;
        if (bin > B) {
          s0 += xr[idx]; s1 += xg[idx]; s2 += xb[idx];
        } else {
          const int k = atomicAdd(&cnt[b], 1);
          if (k < 4096) { candv[b * 4096 + k] = dv[j]; candi[b * 4096 + k] = idx; }
        }
      }
    }
  }
  __shared__ float red[256];
  red[t] = s0; __syncthreads();
  for (int off = 128; off > 0; off >>= 1) { if (t < off) red[t] += red[t + off]; __syncthreads(); }
  if (t == 0) bsums[((size_t)b * 32 + blk) * 3 + 0] = red[0];
  __syncthreads();
  red[t] = s1; __syncthreads();
  for (int off = 128; off > 0; off >>= 1) { if (t < off) red[t] += red[t + off]; __syncthreads(); }
  if (t == 0) bsums[((size_t)b * 32 + blk) * 3 + 1] = red[0];
  __syncthreads();
  red[t] = s2; __syncthreads();
  for (int off = 128; off > 0; off >>= 1) { if (t < off) red[t] += red[t + off]; __syncthreads(); }
  if (t == 0) bsums[((size_t)b * 32 + blk) * 3 + 2] = red[0];
}

// ---------------- finalize A: wave-parallel argmax selection (tie: value desc, index asc) ----------------
__global__ void k_finalA(const float* __restrict__ x, const float* __restrict__ bsums,
                         const int* __restrict__ cnt, const int* __restrict__ rneed,
                         const float* __restrict__ candv, const int* __restrict__ candi,
                         float* __restrict__ Av) {
  const int b = blockIdx.x;
  const int t = threadIdx.x;  // 64 = one wave
  __shared__ float sv[4096];
  __shared__ int si[4096];
  // parallel bsums reduction (32 partials x 3)
  float S0 = 0.f, S1 = 0.f, S2 = 0.f;
  if (t < 32) {
    S0 = bsums[((size_t)b * 32 + t) * 3 + 0];
    S1 = bsums[((size_t)b * 32 + t) * 3 + 1];
    S2 = bsums[((size_t)b * 32 + t) * 3 + 2];
  }
#pragma unroll
  for (int off = 32; off > 0; off >>= 1) {
    S0 += __shfl_xor(S0, off);
    S1 += __shfl_xor(S1, off);
    S2 += __shfl_xor(S2, off);
  }
  const int n = min(cnt[b], 4096);
  const int r = rneed[b];
  for (int i = t; i < n; i += 64) { sv[i] = candv[b * 4096 + i]; si[i] = candi[b * 4096 + i]; }
  __syncthreads();
  const float* xr = x + (size_t)b * 3 * 262144;
  const float* xg = xr + 262144;
  const float* xb = xg + 262144;
  for (int sel = 0; sel < r; ++sel) {
    float bv = -1.f; int bi = 0x7FFFFFFF; int bx = -1;
    for (int i = t; i < n; i += 64) {
      const float v = sv[i];
      const int id = si[i];
      if (v > bv || (v == bv && id < bi)) { bv = v; bi = id; bx = i; }
    }
#pragma unroll
    for (int off = 32; off > 0; off >>= 1) {
      const float ov = __shfl_xor(bv, off);
      const int oid = __shfl_xor(bi, off);
      const int obx = __shfl_xor(bx, off);
      if (ov > bv || (ov == bv && oid < bi)) { bv = ov; bi = oid; bx = obx; }
    }
    if (bx < 0) break;  // uniform across lanes
    if (t == 0) {
      sv[bx] = -1.f;
      S0 += xr[bi]; S1 += xg[bi]; S2 += xb[bi];
    }
    __syncthreads();
  }
  if (t == 0) {
    Av[b * 3 + 0] = S0 / 262.f;
    Av[b * 3 + 1] = S1 / 262.f;
    Av[b * 3 + 2] = S2 / 262.f;
  }
}

// ---------------- fused dc2 + 7x7 min-pool + out-minmax; 16-row tiles ----------------
// 512 blocks = 16 images x 32 tiles. 22 staged hmin rows per 16 output rows (1.375x re-read).
__global__ __launch_bounds__(256) void k_dchv(const float* __restrict__ x,
                                              const float* __restrict__ Av,
                                              const float* __restrict__ params,
                                              float* __restrict__ vm,
                                              float2* __restrict__ pmm) {
  const int lid = blockIdx.x;
  const int swz = (lid & 7) * 64 + (lid >> 3);  // XCD-chunked: image b -> XCD (b>>1)
  const int b = swz >> 5;
  const int y0 = (swz & 31) * 16;
  const int t = threadIdx.x;
  __shared__ float hmin[22][512];
  __shared__ float dcrow[520];
  const float a0 = Av[b * 3 + 0], a1 = Av[b * 3 + 1], a2 = Av[b * 3 + 2];
  const float pb = params[b];
  const float* xb = x + (size_t)b * 3 * 262144;
  float* vmb = vm + (size_t)b * 262144;
  float lmin = FINF, lmax = -FINF;
#pragma unroll 1
  for (int i = 0; i < 22; ++i) {
    const int row = y0 - 3 + i;
    const bool valid = (row >= 0) && (row < 512);
    if (valid) {
      const float2 r = ((const float2*)(xb + (size_t)row * 512))[t];
      const float2 g = ((const float2*)(xb + 262144 + (size_t)row * 512))[t];
      const float2 bl = ((const float2*)(xb + 524288 + (size_t)row * 512))[t];
      dcrow[3 + 2 * t]     = fminf(fminf(r.x / a0, g.x / a1), bl.x / a2);
      dcrow[3 + 2 * t + 1] = fminf(fminf(r.y / a0, g.y / a1), bl.y / a2);
      if (t < 3) { dcrow[t] = FINF; dcrow[515 + t] = FINF; }
    }
    __syncthreads();
    if (valid) {
      float m0 = dcrow[2 * t], m1 = dcrow[2 * t + 1];
#pragma unroll
      for (int k = 1; k < 7; ++k) {
        m0 = fminf(m0, dcrow[2 * t + k]);
        m1 = fminf(m1, dcrow[2 * t + 1 + k]);
      }
      hmin[i][2 * t] = m0;
      hmin[i][2 * t + 1] = m1;
    } else {
      hmin[i][2 * t] = FINF;
      hmin[i][2 * t + 1] = FINF;
    }
    __syncthreads();
    if (i >= 6) {
      const int j = i - 6;
      const int y = y0 + j;
      float2 v = ((const float2*)hmin[j])[t];
#pragma unroll
      for (int k = 1; k < 7; ++k) {
        const float2 h2 = ((const float2*)hmin[j + k])[t];
        v.x = fminf(v.x, h2.x);
        v.y = fminf(v.y, h2.y);
      }
      ((float2*)(vmb + (size_t)y * 512))[t] = v;
      const float T0 = fmaxf(1.f - pb * v.x, 0.01f);
      const float T1 = fmaxf(1.f - pb * v.y, 0.01f);
      const float i0 = 1.f / T0;
      const float i1 = 1.f / T1;
#pragma unroll
      for (int c = 0; c < 3; ++c) {
        const float a = (c == 0) ? a0 : ((c == 1) ? a1 : a2);
        const float2 xv = ((const float2*)(xb + (size_t)c * 262144 + (size_t)y * 512))[t];
        const float o0 = fmaf(xv.x - a, i0, a);
        const float o1 = fmaf(xv.y - a, i1, a);
        lmin = fminf(lmin, fminf(o0, o1));
        lmax = fmaxf(lmax, fmaxf(o0, o1));
      }
    }
  }
  __shared__ float red[256];
  red[t] = lmin; __syncthreads();
  for (int off = 128; off > 0; off >>= 1) { if (t < off) red[t] = fminf(red[t], red[t + off]); __syncthreads(); }
  const float bmin = red[0];
  __syncthreads();
  red[t] = lmax; __syncthreads();
  for (int off = 128; off > 0; off >>= 1) { if (t < off) red[t] = fmaxf(red[t], red[t + off]); __syncthreads(); }
  if (t == 0) pmm[lid] = make_float2(bmin, red[0]);
}

// ---------------- reduce 512 per-block partials -> mm ----------------
__global__ __launch_bounds__(256) void k_redmm(const float2* __restrict__ pmm,
                                               float* __restrict__ mm) {
  const int t = threadIdx.x;
  float mn = FINF, mx = -FINF;
  for (int i = t; i < 512; i += 256) {
    const float2 v = pmm[i];
    mn = fminf(mn, v.x);
    mx = fmaxf(mx, v.y);
  }
  __shared__ float rmn[256], rmx[256];
  rmn[t] = mn; rmx[t] = mx;
  __syncthreads();
  for (int off = 128; off > 0; off >>= 1) {
    if (t < off) {
      rmn[t] = fminf(rmn[t], rmn[t + off]);
      rmx[t] = fmaxf(rmx[t], rmx[t + off]);
    }
    __syncthreads();
  }
  if (t == 0) { mm[0] = rmn[0]; mm[1] = rmx[0]; }
}

// ---------------- final pass: recompute out from x + vm (identical exprs), normalize, write ----------------
__global__ __launch_bounds__(256) void k_norm2(const float* __restrict__ x,
                                               const float* __restrict__ vm,
                                               const float* __restrict__ params,
                                               const float* __restrict__ Av,
                                               const float* __restrict__ mm,
                                               float* __restrict__ out) {
  const int lid = blockIdx.y * gridDim.x + blockIdx.x;   // 8192
  const int swz = (lid & 7) * 1024 + (lid >> 3);         // image b -> XCD (b>>1): vm is L2-local
  const int y = swz & 511, b = swz >> 9;
  const int t = threadIdx.x;
  const float pb = params[b];
  const float a0 = Av[b * 3 + 0], a1 = Av[b * 3 + 1], a2 = Av[b * 3 + 2];
  const float mn = mm[0];
  const float sc = 1.f / (mm[1] - mn);
  const float2 v = ((const float2*)(vm + (size_t)b * 262144 + (size_t)y * 512))[t];
  const float T0 = fmaxf(1.f - pb * v.x, 0.01f);
  const float T1 = fmaxf(1.f - pb * v.y, 0.01f);
  const float i0 = 1.f / T0;
  const float i1 = 1.f / T1;
  const size_t rowoff = (size_t)b * 3 * 262144 + (size_t)y * 512;
#pragma unroll
  for (int c = 0; c < 3; ++c) {
    const float a = (c == 0) ? a0 : ((c == 1) ? a1 : a2);
    const float2 xv = ((const float2*)(x + rowoff + (size_t)c * 262144))[t];
    const float o0 = fmaf(xv.x - a, i0, a);
    const float o1 = fmaf(xv.y - a, i1, a);
    ((float2*)(out + rowoff + (size_t)c * 262144))[t] =
        make_float2((o0 - mn) * sc, (o1 - mn) * sc);
  }
}

extern "C" void kernel_launch(void* const* d_in, const int* in_sizes, int n_in,
                              void* d_out, int out_size, void* d_ws, size_t ws_size,
                              hipStream_t stream) {
  const float* x   = (const float*)d_in[0];
  const float* lat = (const float*)d_in[1];
  const float* w1  = (const float*)d_in[2];
  const float* b1  = (const float*)d_in[3];
  const float* w2  = (const float*)d_in[4];
  const float* b2  = (const float*)d_in[5];
  const float* w3  = (const float*)d_in[6];
  const float* b3  = (const float*)d_in[7];
  float* out = (float*)d_out;

  char* ws = (char*)d_ws;
  size_t off = 0;
  auto alloc = [&](size_t sz) -> void* {
    off = (off + 255) & ~(size_t)255;
    void* p = ws + off;
    off += sz;
    return p;
  };
  // One 16 MB region time-shared: h1part (conv) -> dc (hist/collect) -> vm (dchv/norm2).
  float*    big   = (float*)alloc((size_t)16 * 512 * 512 * sizeof(float));
  float*    h1p   = big;
  float*    dc    = big;
  float*    vmm   = big;
  float*    h1    = (float*)alloc(524288 * sizeof(float));
  unsigned short* wt2 = (unsigned short*)alloc(294912 * sizeof(unsigned short));
  float*    paramsp = (float*)alloc(16 * sizeof(float));
  unsigned* hist  = (unsigned*)alloc(16 * 4096 * sizeof(unsigned));
  int*      Bbin  = (int*)alloc(16 * sizeof(int));
  int*      rneed = (int*)alloc(16 * sizeof(int));
  int*      cnt   = (int*)alloc(16 * sizeof(int));
  float*    bsums = (float*)alloc(16 * 32 * 3 * sizeof(float));
  float*    candv = (float*)alloc(16 * 4096 * sizeof(float));
  int*      candi = (int*)alloc(16 * 4096 * sizeof(int));
  float*    Av    = (float*)alloc(16 * 3 * sizeof(float));
  float2*   pmm   = (float2*)alloc(512 * sizeof(float2));
  float*    mm    = (float*)alloc(2 * sizeof(float));

  k_prep<<<1152, 256, 0, stream>>>(w1, wt2, hist, cnt);
  k_conv1m<<<dim3(16, 8, 2), 512, 0, stream>>>(lat, wt2, h1p);
  k_combine<<<512, 256, 0, stream>>>(h1p, h1, b1);
  k_conv2<<<16, 256, 0, stream>>>(h1, w2, b2, w3, b3, paramsp);
  k_hist<<<512, 256, 0, stream>>>(x, hist, dc);
  k_scan<<<16, 256, 0, stream>>>(hist, Bbin, rneed);
  k_collect<<<512, 256, 0, stream>>>(x, dc, Bbin, cnt, candv, candi, bsums);
  k_finalA<<<16, 64, 0, stream>>>(x, bsums, cnt, rneed, candv, candi, Av);
  k_dchv<<<512, 256, 0, stream>>>(x, Av, paramsp, vmm, pmm);
  k_redmm<<<1, 256, 0, stream>>>(pmm, mm);
  k_norm2<<<dim3(512, 16), 256, 0, stream>>>(x, vmm, paramsp, Av, mm, out);
}

// Round 9
// 142.577 us; speedup vs baseline: 2.0991x; 1.0166x over previous
//
#include <hip/hip_runtime.h>
#include <math.h>

#define FINF 3.0e38f

typedef __attribute__((ext_vector_type(8))) short short8v;   // 8 bf16 (4 VGPRs)
typedef __attribute__((ext_vector_type(4))) float float4v;   // MFMA acc

__device__ __forceinline__ unsigned short f2bf(float f) {
  unsigned u = __float_as_uint(f);
  unsigned r = u + 0x7FFFu + ((u >> 16) & 1u);  // RNE
  return (unsigned short)(r >> 16);
}

// ---------------- prep: W1 -> bf16 wt2[tap][oc][ic]; zero hist/cnt ----------------
__global__ void k_prep(const float* __restrict__ w1, unsigned short* __restrict__ wt2,
                       unsigned* __restrict__ hist, int* __restrict__ cnt) {
  const int idx = blockIdx.x * 256 + threadIdx.x;  // 294912 = 9*128*256
  if (idx < 294912) {
    const int ic = idx & 255;
    const int r = idx >> 8;
    const int oc = r & 127;
    const int tap = r >> 7;
    wt2[idx] = f2bf(w1[((size_t)oc * 256 + ic) * 9 + tap]);
  }
  if (idx < 16 * 4096) hist[idx] = 0u;
  if (idx < 16) cnt[idx] = 0;
}

// ---------------- conv1 via MFMA (round-7 form, verified) ----------------
__global__ __launch_bounds__(512) void k_conv1m(const float* __restrict__ lat,
                                                const unsigned short* __restrict__ wt2,
                                                float* __restrict__ h1part) {
  const int b = blockIdx.x, ks = blockIdx.y, nh = blockIdx.z;
  const int t = threadIdx.x;
  __shared__ unsigned short sA[1025 * 40];  // 82 KB
  {
    const float4* src = (const float4*)lat + ((size_t)b * 256 + ks * 32) * 256;
#pragma unroll
    for (int i = t; i < 8192; i += 512) {
      const int ic = i >> 8;
      const int q = i & 255;
      const float4 v = src[ic * 256 + q];
      const int px0 = q * 4;
      sA[(px0 + 0) * 40 + ic] = f2bf(v.x);
      sA[(px0 + 1) * 40 + ic] = f2bf(v.y);
      sA[(px0 + 2) * 40 + ic] = f2bf(v.z);
      sA[(px0 + 3) * 40 + ic] = f2bf(v.w);
    }
    if (t < 40) sA[1024 * 40 + t] = 0;
  }
  __syncthreads();

  const int lane = t & 63, wid = t >> 6;
  const int ocbase = nh * 64 + (wid & 1) * 32;
  const int pxbase = (wid >> 1) * 64;
  const int l15 = lane & 15, lg = lane >> 4;

  float4v acc[2][4];
#pragma unroll
  for (int f = 0; f < 2; ++f)
#pragma unroll
    for (int g = 0; g < 4; ++g) acc[f][g] = (float4v){0.f, 0.f, 0.f, 0.f};

#pragma unroll
  for (int tap = 0; tap < 9; ++tap) {
    const int ky = tap / 3, kx = tap % 3;
    short8v aW[2];
#pragma unroll
    for (int f = 0; f < 2; ++f) {
      const int oc = ocbase + f * 16 + l15;
      aW[f] = *(const short8v*)(wt2 + (size_t)(tap * 128 + oc) * 256 + ks * 32 + lg * 8);
    }
    short8v bL[4];
#pragma unroll
    for (int g = 0; g < 4; ++g) {
      const int px = pxbase + g * 16 + l15;
      const int iy = 2 * (px >> 4) - 1 + ky;
      const int ix = 2 * (px & 15) - 1 + kx;
      const int p = (iy >= 0 && ix >= 0) ? iy * 32 + ix : 1024;
      bL[g] = *(const short8v*)(sA + p * 40 + lg * 8);
    }
#pragma unroll
    for (int f = 0; f < 2; ++f)
#pragma unroll
      for (int g = 0; g < 4; ++g)
        acc[f][g] = __builtin_amdgcn_mfma_f32_16x16x32_bf16(aW[f], bL[g], acc[f][g], 0, 0, 0);
  }

  float* dst = h1part + (size_t)ks * 524288 + (size_t)b * 32768;
#pragma unroll
  for (int f = 0; f < 2; ++f)
#pragma unroll
    for (int g = 0; g < 4; ++g)
#pragma unroll
      for (int r = 0; r < 4; ++r) {
        const int oc = ocbase + f * 16 + lg * 4 + r;
        const int px = pxbase + g * 16 + l15;
        dst[oc * 256 + px] = acc[f][g][r];
      }
}

// ---------------- combine 8 ksplit partials + bias + leaky ----------------
__global__ void k_combine(const float* __restrict__ h1p, float* __restrict__ h1,
                          const float* __restrict__ b1) {
  const int i = blockIdx.x * 256 + threadIdx.x;  // float4 index, 131072 total
  const float4* p = (const float4*)h1p;
  float4 a = p[i];
#pragma unroll
  for (int ks = 1; ks < 8; ++ks) {
    const float4 q = p[(size_t)ks * 131072 + i];
    a.x += q.x; a.y += q.y; a.z += q.z; a.w += q.w;
  }
  const int oc = (i >> 6) & 127;
  const float bias = b1[oc];
  float s;
  s = a.x + bias; a.x = s >= 0.f ? s : 0.02f * s;
  s = a.y + bias; a.y = s >= 0.f ? s : 0.02f * s;
  s = a.z + bias; a.z = s >= 0.f ? s : 0.02f * s;
  s = a.w + bias; a.w = s >= 0.f ? s : 0.02f * s;
  ((float4*)h1)[i] = a;
}

// ---------------- conv2 + mean + 1x1 conv + tanh -> params[b] ----------------
__global__ __launch_bounds__(256) void k_conv2(const float* __restrict__ h1,
                                               const float* __restrict__ w2,
                                               const float* __restrict__ b2,
                                               const float* __restrict__ w3,
                                               const float* __restrict__ b3,
                                               float* __restrict__ params) {
  const int b = blockIdx.x;
  const int t = threadIdx.x;
  __shared__ float sW[1152];
  __shared__ float red[256];
  for (int i = t; i < 1152; i += 256) sW[i] = w2[i];
  __syncthreads();
  const int pix = t >> 2, icq = t & 3;
  const int oy = pix >> 3, ox = pix & 7;
  const float* hb = h1 + (size_t)b * 128 * 256;
  float s = 0.f;
  for (int ic = icq * 32; ic < icq * 32 + 32; ++ic) {
    const float* hp = hb + ic * 256;
#pragma unroll
    for (int ky = 0; ky < 3; ++ky) {
      const int iy = 2 * oy - 1 + ky;
      if (iy < 0) continue;
#pragma unroll
      for (int kx = 0; kx < 3; ++kx) {
        const int ix = 2 * ox - 1 + kx;
        if (ix < 0) continue;
        s += sW[ic * 9 + ky * 3 + kx] * hp[iy * 16 + ix];
      }
    }
  }
  red[t] = s;
  __syncthreads();
  for (int off = 128; off > 0; off >>= 1) {
    if (t < off) red[t] += red[t + off];
    __syncthreads();
  }
  if (t == 0) {
    const float mean = red[0] / 64.f + b2[0];
    const float h = w3[0] * mean + b3[0];
    params[b] = tanhf(h) * 0.5f + 0.5f;
  }
}

// ---------------- histogram of dark channel (also writes dc); XCD-pinned per image ----------------
__global__ __launch_bounds__(256) void k_hist(const float* __restrict__ x,
                                              unsigned* __restrict__ ghist,
                                              float* __restrict__ dc) {
  const int lid = blockIdx.x;
  const int b = (lid & 7) | (((lid >> 3) & 1) << 3);
  const int blk = lid >> 4;
  const int t = threadIdx.x;
  __shared__ unsigned lh[4096];
  for (int i = t; i < 4096; i += 256) lh[i] = 0u;
  __syncthreads();
  const float* xr = x + (size_t)b * 3 * 262144;
  const float* xg = xr + 262144;
  const float* xb = xg + 262144;
  float4* dcb = (float4*)(dc + (size_t)b * 262144);
  const int f0 = blk * 2048;
#pragma unroll
  for (int i = 0; i < 8; ++i) {
    const int f4 = f0 + t + i * 256;
    const float4 r = ((const float4*)xr)[f4];
    const float4 g = ((const float4*)xg)[f4];
    const float4 bl = ((const float4*)xb)[f4];
    float4 d4;
    d4.x = fminf(fminf(r.x, g.x), bl.x); atomicAdd(&lh[min(4095, (int)(d4.x * 4096.f))], 1u);
    d4.y = fminf(fminf(r.y, g.y), bl.y); atomicAdd(&lh[min(4095, (int)(d4.y * 4096.f))], 1u);
    d4.z = fminf(fminf(r.z, g.z), bl.z); atomicAdd(&lh[min(4095, (int)(d4.z * 4096.f))], 1u);
    d4.w = fminf(fminf(r.w, g.w), bl.w); atomicAdd(&lh[min(4095, (int)(d4.w * 4096.f))], 1u);
    dcb[f4] = d4;
  }
  __syncthreads();
  for (int i = t; i < 4096; i += 256)
    if (lh[i]) atomicAdd(&ghist[b * 4096 + i], lh[i]);
}

// ---------------- collect (with inline threshold scan): sums above bin + boundary candidates ----------------
__global__ __launch_bounds__(256) void k_collect(const float* __restrict__ x,
                                                 const float* __restrict__ dc,
                                                 const unsigned* __restrict__ ghist,
                                                 int* __restrict__ cnt,
                                                 float* __restrict__ candv,
                                                 int* __restrict__ candi,
                                                 float* __restrict__ bsums) {
  const int lid = blockIdx.x;  // same mapping as k_hist
  const int b = (lid & 7) | (((lid >> 3) & 1) << 3);
  const int blk = lid >> 4;
  const int t = threadIdx.x;
  // inline scan -> threshold bin B
  __shared__ unsigned h[4096];
  __shared__ unsigned csum[256];
  __shared__ int sB;
  for (int i = t; i < 4096; i += 256) h[i] = ghist[b * 4096 + i];
  __syncthreads();
  const int top = 4095 - 16 * t;
  unsigned s = 0;
#pragma unroll
  for (int k = 0; k < 16; ++k) s += h[top - k];
  csum[t] = s;
  __syncthreads();
  for (int off = 1; off < 256; off <<= 1) {
    const unsigned add = (t >= off) ? csum[t - off] : 0u;
    __syncthreads();
    csum[t] += add;
    __syncthreads();
  }
  {
    const unsigned incl = csum[t];
    const unsigned before = incl - s;
    if (before < 262u && incl >= 262u) {
      unsigned cum = before;
      for (int k = 0; k < 16; ++k) {
        const unsigned c = h[top - k];
        if (cum + c >= 262u) { sB = top - k; break; }
        cum += c;
      }
    }
  }
  __syncthreads();
  const int B = sB;
  const float* xr = x + (size_t)b * 3 * 262144;
  const float* xg = xr + 262144;
  const float* xb = xg + 262144;
  const float4* dcb = (const float4*)(dc + (size_t)b * 262144);
  const int f0 = blk * 2048;
  float s0 = 0.f, s1 = 0.f, s2 = 0.f;
#pragma unroll
  for (int i = 0; i < 8; ++i) {
    const int f4 = f0 + t + i * 256;
    const float4 d4 = dcb[f4];
    const float dv[4] = {d4.x, d4.y, d4.z, d4.w};
#pragma unroll
    for (int j = 0; j < 4; ++j) {
      const int bin = min(4095, (int)(dv[j] * 4096.f));
      if (bin >= B) {
        const int idx = f4 * 4 + j;
        if (bin > B) {
          s0 += xr[idx]; s1 += xg[idx]; s2 += xb[idx];
        } else {
          const int k = atomicAdd(&cnt[b], 1);
          if (k < 4096) { candv[b * 4096 + k] = dv[j]; candi[b * 4096 + k] = idx; }
        }
      }
    }
  }
  __shared__ float red[256];
  red[t] = s0; __syncthreads();
  for (int off = 128; off > 0; off >>= 1) { if (t < off) red[t] += red[t + off]; __syncthreads(); }
  if (t == 0) bsums[((size_t)b * 32 + blk) * 3 + 0] = red[0];
  __syncthreads();
  red[t] = s1; __syncthreads();
  for (int off = 128; off > 0; off >>= 1) { if (t < off) red[t] += red[t + off]; __syncthreads(); }
  if (t == 0) bsums[((size_t)b * 32 + blk) * 3 + 1] = red[0];
  __syncthreads();
  red[t] = s2; __syncthreads();
  for (int off = 128; off > 0; off >>= 1) { if (t < off) red[t] += red[t + off]; __syncthreads(); }
  if (t == 0) bsums[((size_t)b * 32 + blk) * 3 + 2] = red[0];
}

// ---------------- finalize A: inline rneed scan + wave-parallel argmax selection ----------------
__global__ void k_finalA(const float* __restrict__ x, const float* __restrict__ bsums,
                         const int* __restrict__ cnt, const unsigned* __restrict__ ghist,
                         const float* __restrict__ candv, const int* __restrict__ candi,
                         float* __restrict__ Av) {
  const int b = blockIdx.x;
  const int t = threadIdx.x;  // 64 = one wave
  __shared__ float sv[4096];
  __shared__ int si[4096];
  __shared__ int sR;
  // inline scan for rneed: thread t covers bins [4095-64t .. 4095-64t-63]
  {
    const int base = 4095 - 64 * t;
    unsigned ssum = 0;
    for (int k = 0; k < 64; ++k) ssum += ghist[b * 4096 + base - k];
    unsigned incl = ssum;
    for (int off = 1; off < 64; off <<= 1) {
      const unsigned v = __shfl_up(incl, off);
      if (t >= off) incl += v;
    }
    const unsigned before = incl - ssum;
    if (before < 262u && incl >= 262u) {
      unsigned cum = before;
      for (int k = 0; k < 64; ++k) {
        const unsigned c = ghist[b * 4096 + base - k];
        if (cum + c >= 262u) { sR = (int)(262u - cum); break; }
        cum += c;
      }
    }
  }
  // parallel bsums reduction (32 partials x 3)
  float S0 = 0.f, S1 = 0.f, S2 = 0.f;
  if (t < 32) {
    S0 = bsums[((size_t)b * 32 + t) * 3 + 0];
    S1 = bsums[((size_t)b * 32 + t) * 3 + 1];
    S2 = bsums[((size_t)b * 32 + t) * 3 + 2];
  }
#pragma unroll
  for (int off = 32; off > 0; off >>= 1) {
    S0 += __shfl_xor(S0, off);
    S1 += __shfl_xor(S1, off);
    S2 += __shfl_xor(S2, off);
  }
  const int n = min(cnt[b], 4096);
  for (int i = t; i < n; i += 64) { sv[i] = candv[b * 4096 + i]; si[i] = candi[b * 4096 + i]; }
  __syncthreads();
  const int r = sR;
  const float* xr = x + (size_t)b * 3 * 262144;
  const float* xg = xr + 262144;
  const float* xb = xg + 262144;
  for (int sel = 0; sel < r; ++sel) {
    float bv = -1.f; int bi = 0x7FFFFFFF; int bx = -1;
    for (int i = t; i < n; i += 64) {
      const float v = sv[i];
      const int id = si[i];
      if (v > bv || (v == bv && id < bi)) { bv = v; bi = id; bx = i; }
    }
#pragma unroll
    for (int off = 32; off > 0; off >>= 1) {
      const float ov = __shfl_xor(bv, off);
      const int oid = __shfl_xor(bi, off);
      const int obx = __shfl_xor(bx, off);
      if (ov > bv || (ov == bv && oid < bi)) { bv = ov; bi = oid; bx = obx; }
    }
    if (bx < 0) break;  // uniform across lanes
    if (t == 0) {
      sv[bx] = -1.f;
      S0 += xr[bi]; S1 += xg[bi]; S2 += xb[bi];
    }
    __syncthreads();
  }
  if (t == 0) {
    Av[b * 3 + 0] = S0 / 262.f;
    Av[b * 3 + 1] = S1 / 262.f;
    Av[b * 3 + 2] = S2 / 262.f;
  }
}

// ---------------- fused dc2 + 7x7 min-pool + out-minmax; 8-row tiles, 2 rows per barrier-pair ----------------
// 1024 blocks = 16 images x 128 tiles... (16 images x 64 tiles of 8 rows). 14 barriers/block.
__global__ __launch_bounds__(256) void k_dchv(const float* __restrict__ x,
                                              const float* __restrict__ Av,
                                              const float* __restrict__ params,
                                              float* __restrict__ vm,
                                              float2* __restrict__ pmm) {
  const int lid = blockIdx.x;                    // 1024
  const int swz = (lid & 7) * 128 + (lid >> 3);  // XCD-chunked: image b -> XCD (b>>1)
  const int b = swz >> 6;
  const int y0 = (swz & 63) * 8;
  const int t = threadIdx.x;
  __shared__ float dcrow2[2][520];
  __shared__ float hmin[14][512];
  const float a0 = Av[b * 3 + 0], a1 = Av[b * 3 + 1], a2 = Av[b * 3 + 2];
  const float pb = params[b];
  const float* xb = x + (size_t)b * 3 * 262144;
  float* vmb = vm + (size_t)b * 262144;
  float lmin = FINF, lmax = -FINF;
  const int half = t >> 7;
  const int c0 = (t & 127) * 4;
#pragma unroll 1
  for (int d = 0; d < 7; ++d) {
    const int i = 2 * d + half;
    const int row = y0 - 3 + i;
    const bool valid = (row >= 0) && (row < 512);
    if (valid) {
      const float4 r  = *(const float4*)(xb + (size_t)row * 512 + c0);
      const float4 g  = *(const float4*)(xb + 262144 + (size_t)row * 512 + c0);
      const float4 bl = *(const float4*)(xb + 524288 + (size_t)row * 512 + c0);
      float* dr = dcrow2[half];
      dr[3 + c0 + 0] = fminf(fminf(r.x / a0, g.x / a1), bl.x / a2);
      dr[3 + c0 + 1] = fminf(fminf(r.y / a0, g.y / a1), bl.y / a2);
      dr[3 + c0 + 2] = fminf(fminf(r.z / a0, g.z / a1), bl.z / a2);
      dr[3 + c0 + 3] = fminf(fminf(r.w / a0, g.w / a1), bl.w / a2);
      if (c0 == 0) {
        dr[0] = FINF; dr[1] = FINF; dr[2] = FINF;
        dr[515] = FINF; dr[516] = FINF; dr[517] = FINF;
      }
    }
    __syncthreads();
    {
      float* hm = hmin[i];
      if (valid) {
        const float* dr = dcrow2[half];
#pragma unroll
        for (int k2 = 0; k2 < 4; ++k2) {
          float m = dr[c0 + k2];
#pragma unroll
          for (int k = 1; k < 7; ++k) m = fminf(m, dr[c0 + k2 + k]);
          hm[c0 + k2] = m;
        }
      } else {
#pragma unroll
        for (int k2 = 0; k2 < 4; ++k2) hm[c0 + k2] = FINF;
      }
    }
    __syncthreads();
    if (d >= 3) {
#pragma unroll
      for (int jj = 0; jj < 2; ++jj) {
        const int j = 2 * (d - 3) + jj;
        const int y = y0 + j;
        float2 v = ((const float2*)hmin[j])[t];
#pragma unroll
        for (int k = 1; k < 7; ++k) {
          const float2 h2 = ((const float2*)hmin[j + k])[t];
          v.x = fminf(v.x, h2.x);
          v.y = fminf(v.y, h2.y);
        }
        ((float2*)(vmb + (size_t)y * 512))[t] = v;
        const float T0 = fmaxf(1.f - pb * v.x, 0.01f);
        const float T1 = fmaxf(1.f - pb * v.y, 0.01f);
        const float i0 = 1.f / T0;
        const float i1 = 1.f / T1;
#pragma unroll
        for (int c = 0; c < 3; ++c) {
          const float a = (c == 0) ? a0 : ((c == 1) ? a1 : a2);
          const float2 xv = ((const float2*)(xb + (size_t)c * 262144 + (size_t)y * 512))[t];
          const float o0 = fmaf(xv.x - a, i0, a);
          const float o1 = fmaf(xv.y - a, i1, a);
          lmin = fminf(lmin, fminf(o0, o1));
          lmax = fmaxf(lmax, fmaxf(o0, o1));
        }
      }
    }
  }
  __shared__ float red[256];
  red[t] = lmin; __syncthreads();
  for (int off = 128; off > 0; off >>= 1) { if (t < off) red[t] = fminf(red[t], red[t + off]); __syncthreads(); }
  const float bmin = red[0];
  __syncthreads();
  red[t] = lmax; __syncthreads();
  for (int off = 128; off > 0; off >>= 1) { if (t < off) red[t] = fmaxf(red[t], red[t + off]); __syncthreads(); }
  if (t == 0) pmm[lid] = make_float2(bmin, red[0]);
}

// ---------------- reduce 1024 per-block partials -> mm ----------------
__global__ __launch_bounds__(256) void k_redmm(const float2* __restrict__ pmm,
                                               float* __restrict__ mm) {
  const int t = threadIdx.x;
  float mn = FINF, mx = -FINF;
  for (int i = t; i < 1024; i += 256) {
    const float2 v = pmm[i];
    mn = fminf(mn, v.x);
    mx = fmaxf(mx, v.y);
  }
  __shared__ float rmn[256], rmx[256];
  rmn[t] = mn; rmx[t] = mx;
  __syncthreads();
  for (int off = 128; off > 0; off >>= 1) {
    if (t < off) {
      rmn[t] = fminf(rmn[t], rmn[t + off]);
      rmx[t] = fmaxf(rmx[t], rmx[t + off]);
    }
    __syncthreads();
  }
  if (t == 0) { mm[0] = rmn[0]; mm[1] = rmx[0]; }
}

// ---------------- final pass: 2 rows/block, float4; recompute out (identical exprs), normalize ----------------
__global__ __launch_bounds__(256) void k_norm2(const float* __restrict__ x,
                                               const float* __restrict__ vm,
                                               const float* __restrict__ params,
                                               const float* __restrict__ Av,
                                               const float* __restrict__ mm,
                                               float* __restrict__ out) {
  const int lid = blockIdx.x;                    // 4096
  const int swz = (lid & 7) * 512 + (lid >> 3);  // image b -> XCD (b>>1): vm is L2-local
  const int b = swz >> 8;
  const int y = (swz & 255) * 2 + (threadIdx.x >> 7);
  const int c0 = (threadIdx.x & 127) * 4;
  const float pb = params[b];
  const float a0 = Av[b * 3 + 0], a1 = Av[b * 3 + 1], a2 = Av[b * 3 + 2];
  const float mn = mm[0];
  const float sc = 1.f / (mm[1] - mn);
  const float4 v = *(const float4*)(vm + (size_t)b * 262144 + (size_t)y * 512 + c0);
  const float i0 = 1.f / fmaxf(1.f - pb * v.x, 0.01f);
  const float i1 = 1.f / fmaxf(1.f - pb * v.y, 0.01f);
  const float i2 = 1.f / fmaxf(1.f - pb * v.z, 0.01f);
  const float i3 = 1.f / fmaxf(1.f - pb * v.w, 0.01f);
  const size_t rowoff = (size_t)b * 3 * 262144 + (size_t)y * 512 + c0;
#pragma unroll
  for (int c = 0; c < 3; ++c) {
    const float a = (c == 0) ? a0 : ((c == 1) ? a1 : a2);
    const float4 xv = *(const float4*)(x + rowoff + (size_t)c * 262144);
    float4 o;
    o.x = (fmaf(xv.x - a, i0, a) - mn) * sc;
    o.y = (fmaf(xv.y - a, i1, a) - mn) * sc;
    o.z = (fmaf(xv.z - a, i2, a) - mn) * sc;
    o.w = (fmaf(xv.w - a, i3, a) - mn) * sc;
    *(float4*)(out + rowoff + (size_t)c * 262144) = o;
  }
}

extern "C" void kernel_launch(void* const* d_in, const int* in_sizes, int n_in,
                              void* d_out, int out_size, void* d_ws, size_t ws_size,
                              hipStream_t stream) {
  const float* x   = (const float*)d_in[0];
  const float* lat = (const float*)d_in[1];
  const float* w1  = (const float*)d_in[2];
  const float* b1  = (const float*)d_in[3];
  const float* w2  = (const float*)d_in[4];
  const float* b2  = (const float*)d_in[5];
  const float* w3  = (const float*)d_in[6];
  const float* b3  = (const float*)d_in[7];
  float* out = (float*)d_out;

  char* ws = (char*)d_ws;
  size_t off = 0;
  auto alloc = [&](size_t sz) -> void* {
    off = (off + 255) & ~(size_t)255;
    void* p = ws + off;
    off += sz;
    return p;
  };
  // One 16 MB region time-shared: h1part (conv) -> dc (hist/collect) -> vm (dchv/norm2).
  float*    big   = (float*)alloc((size_t)16 * 512 * 512 * sizeof(float));
  float*    h1p   = big;
  float*    dc    = big;
  float*    vmm   = big;
  float*    h1    = (float*)alloc(524288 * sizeof(float));
  unsigned short* wt2 = (unsigned short*)alloc(294912 * sizeof(unsigned short));
  float*    paramsp = (float*)alloc(16 * sizeof(float));
  unsigned* hist  = (unsigned*)alloc(16 * 4096 * sizeof(unsigned));
  int*      cnt   = (int*)alloc(16 * sizeof(int));
  float*    bsums = (float*)alloc(16 * 32 * 3 * sizeof(float));
  float*    candv = (float*)alloc(16 * 4096 * sizeof(float));
  int*      candi = (int*)alloc(16 * 4096 * sizeof(int));
  float*    Av    = (float*)alloc(16 * 3 * sizeof(float));
  float2*   pmm   = (float2*)alloc(1024 * sizeof(float2));
  float*    mm    = (float*)alloc(2 * sizeof(float));

  k_prep<<<1152, 256, 0, stream>>>(w1, wt2, hist, cnt);
  k_conv1m<<<dim3(16, 8, 2), 512, 0, stream>>>(lat, wt2, h1p);
  k_combine<<<512, 256, 0, stream>>>(h1p, h1, b1);
  k_conv2<<<16, 256, 0, stream>>>(h1, w2, b2, w3, b3, paramsp);
  k_hist<<<512, 256, 0, stream>>>(x, hist, dc);
  k_collect<<<512, 256, 0, stream>>>(x, dc, hist, cnt, candv, candi, bsums);
  k_finalA<<<16, 64, 0, stream>>>(x, bsums, cnt, hist, candv, candi, Av);
  k_dchv<<<1024, 256, 0, stream>>>(x, Av, paramsp, vmm, pmm);
  k_redmm<<<1, 256, 0, stream>>>(pmm, mm);
  k_norm2<<<4096, 256, 0, stream>>>(x, vmm, paramsp, Av, mm, out);
}